// Round 19
// baseline (961.666 us; speedup 1.0000x reference)
//
#include <hip/hip_runtime.h>
#include <hip/hip_bf16.h>

typedef unsigned short u16;
typedef unsigned int u32;
typedef __attribute__((ext_vector_type(8))) short bf16x8;
typedef __attribute__((ext_vector_type(4))) float f32x4;

#define T_TOK 3600
#define D_    512
#define H_    8
#define HD    64
#define NKT   57
#define VT_S  3648
#define KSPLIT 8
#define ZSLICE 1843200  // u16 per z-slice: 8*3600*64
#define QKS   1024      // qkvb row stride (Q|K only)
#define SQRT512 22.627416997969522f
#define QK_SCALE 0.18033688011112042f // 0.125 * log2(e)

__device__ __forceinline__ u16 f2bf(float f) {
    unsigned int x = __float_as_uint(f);
    unsigned int lsb = (x >> 16) & 1;
    return (u16)((x + 0x7fffu + lsb) >> 16);
}
__device__ __forceinline__ float bf2f(u16 u) {
    return __uint_as_float(((unsigned int)u) << 16);
}
__device__ __forceinline__ u32 cvt_pk_bf16(float a, float b) {
    u32 r;
    asm("v_cvt_pk_bf16_f32 %0, %1, %2" : "=v"(r) : "v"(a), "v"(b));
    return r;
}
__device__ __forceinline__ void async_ld16(const void* g, void* l) {
    __builtin_amdgcn_global_load_lds(
        (const __attribute__((address_space(1))) void*)g,
        (__attribute__((address_space(3))) void*)l, 16, 0, 0);
}
__device__ __forceinline__ int step_of(int i) {
    return (i < 3000) ? (i / 10) : ((i < 3300) ? (i - 3000) : (i - 3300));
}
__device__ __forceinline__ void tile_minmax(int kbase, int& mn, int& mx) {
    int a = kbase, b = min(kbase + 63, T_TOK - 1);
    mn = 0x7fffffff; mx = -1;
    if (a < 3000)              { mn = min(mn, a / 10);              mx = max(mx, min(b, 2999) / 10); }
    if (b >= 3000 && a < 3300) { mn = min(mn, max(a, 3000) - 3000); mx = max(mx, min(b, 3299) - 3000); }
    if (b >= 3300)             { mn = min(mn, max(a, 3300) - 3300); mx = max(mx, b - 3300); }
}

// ---------------- gather: IN[3600][24] + cls rows of x and xb --------------
__global__ __launch_bounds__(256) void gather_kernel(
    const float* __restrict__ pxs, const float* __restrict__ pys, const float* __restrict__ phs,
    const float* __restrict__ bxs, const float* __restrict__ bys, const float* __restrict__ bzs,
    const float* __restrict__ emb_table, const float* __restrict__ ball_emb,
    const float* __restrict__ cls_emb, const int* __restrict__ pidx,
    float* __restrict__ IN, float* __restrict__ x, u16* __restrict__ xb)
{
    int g = blockIdx.x * 256 + threadIdx.x;
    if (g < 3300) {
        float* row = IN + g * 24;
        if (g < 3000) {
            int id = pidx[g];
            #pragma unroll
            for (int e = 0; e < 20; e++) row[e] = emb_table[id * 20 + e];
            row[20] = pxs[g]; row[21] = pys[g]; row[22] = phs[g];
        } else {
            int b = g - 3000;
            #pragma unroll
            for (int e = 0; e < 20; e++) row[e] = ball_emb[e];
            row[20] = bxs[b]; row[21] = bys[b]; row[22] = bzs[b];
        }
        row[23] = 0.f;
    }
    for (int i = g; i < 300 * 512; i += 3840) {
        float v = cls_emb[i & 511];
        x[3300 * 512 + i] = v;
        xb[3300 * 512 + i] = f2bf(v);
    }
}

// ---------------- per-layer weight convert + vt-pad zero -------------------
__global__ __launch_bounds__(256) void w2b4_kernel(
    const float* __restrict__ s0, const float* __restrict__ s1,
    const float* __restrict__ s2, const float* __restrict__ s3,
    u16* __restrict__ dst, u16* __restrict__ vt)
{
    int stride = gridDim.x * 256;
    for (int i = blockIdx.x * 256 + threadIdx.x; i < 786432; i += stride) {
        const float4* src;
        int j = i;
        if (j < 196608)      { src = (const float4*)s0; }
        else if (j < 262144) { src = (const float4*)s1; j -= 196608; }
        else if (j < 524288) { src = (const float4*)s2; j -= 262144; }
        else                 { src = (const float4*)s3; j -= 524288; }
        float4 v = src[j];
        ushort4 o;
        o.x = f2bf(v.x); o.y = f2bf(v.y); o.z = f2bf(v.z); o.w = f2bf(v.w);
        reinterpret_cast<ushort4*>(dst)[i] = o;
    }
    // zero vt's pad tokens [3600,3648) on all 512 rows
    for (int i = blockIdx.x * 256 + threadIdx.x; i < 512 * 64; i += stride) {
        int row = i >> 6, c = i & 63;
        if (c < 48) vt[(size_t)row * VT_S + 3600 + c] = 0;
    }
}

// ---------------- head-weight + bias pack ----------------------------------
__global__ __launch_bounds__(256) void w2bh_kernel(
    const float* __restrict__ cp, const float* __restrict__ cb,
    const float* __restrict__ cs, const float* __restrict__ bp,
    const float* __restrict__ bb, const float* __restrict__ bs,
    u16* __restrict__ dst, float* __restrict__ bias)
{
    int stride = gridDim.x * 256;
    for (int i = blockIdx.x * 256 + threadIdx.x; i < 187136; i += stride) {
        const float4* src;
        int j = i;
        if (j < 15488)       { src = (const float4*)cp; }
        else if (j < 185856) { src = (const float4*)cb; j -= 15488; }
        else                 { src = (const float4*)cs; j -= 185856; }
        float4 v = src[j];
        ushort4 o;
        o.x = f2bf(v.x); o.y = f2bf(v.y); o.z = f2bf(v.z); o.w = f2bf(v.w);
        reinterpret_cast<ushort4*>(dst)[i] = o;
    }
    int g = blockIdx.x * 256 + threadIdx.x;
    if (g < 1462)
        bias[g] = (g < 121) ? bp[g] : (g < 1452) ? bb[g - 121] : bs[g - 1452];
}

// ---------------- fp32-input token GEMM: player(z=0) / ball(z=1) ----------
__device__ __forceinline__ void stage_f32(
    const float* __restrict__ src, int nrows, int K, int lda,
    int r0, int kk, int srow, int scg, u16* dst)
{
    u16 tmp[16];
    int rr = r0 + srow;
    if (rr < nrows) {
        if (((lda & 3) == 0) && (kk + scg + 16 <= K)) {
            const float4* p = reinterpret_cast<const float4*>(src + (size_t)rr * lda + kk + scg);
            #pragma unroll
            for (int q = 0; q < 4; q++) {
                float4 v = p[q];
                tmp[q*4+0] = f2bf(v.x); tmp[q*4+1] = f2bf(v.y);
                tmp[q*4+2] = f2bf(v.z); tmp[q*4+3] = f2bf(v.w);
            }
        } else {
            #pragma unroll
            for (int e = 0; e < 16; e++) {
                int kc = kk + scg + e;
                tmp[e] = (kc < K) ? f2bf(src[(size_t)rr * lda + kc]) : (u16)0;
            }
        }
    } else {
        #pragma unroll
        for (int e = 0; e < 16; e++) tmp[e] = 0;
    }
    *reinterpret_cast<bf16x8*>(dst)     = *reinterpret_cast<const bf16x8*>(&tmp[0]);
    *reinterpret_cast<bf16x8*>(dst + 8) = *reinterpret_cast<const bf16x8*>(&tmp[8]);
}

template<int RELU, int DUAL>
__global__ __launch_bounds__(256) void gemm_tok(
    const float* __restrict__ A0, const float* __restrict__ W0p,
    const float* __restrict__ b0p, float* __restrict__ C0,
    const float* __restrict__ A1, const float* __restrict__ W1p,
    const float* __restrict__ b1p, float* __restrict__ C1,
    u16* __restrict__ Cb,
    int M0, int M1, int N, int K, int lda, float scale)
{
    int zz = blockIdx.z;
    int M = zz ? M1 : M0;
    int m0 = blockIdx.x * 128;
    if (m0 >= M) return;
    const float* A = zz ? A1 : A0;
    const float* W = zz ? W1p : W0p;
    const float* bias = zz ? b1p : b0p;
    float* C = zz ? C1 : C0;
    u16* CbL = DUAL ? (zz ? Cb + (size_t)M0 * N : Cb) : nullptr;

    __shared__ u16 As[128][40];
    __shared__ u16 Bs[128][40];
    int t = threadIdx.x;
    int w = t >> 6, l = t & 63;
    int ll = l & 15, lg = l >> 4;
    int wr = w >> 1, wc = w & 1;
    int n0 = blockIdx.y * 128;
    int srow = t >> 1;
    int scg  = (t & 1) * 16;

    f32x4 acc[4][4];
    #pragma unroll
    for (int i = 0; i < 4; i++)
        #pragma unroll
        for (int j = 0; j < 4; j++) acc[i][j] = (f32x4){0.f, 0.f, 0.f, 0.f};

    for (int kk = 0; kk < K; kk += 32) {
        stage_f32(A, M, K, lda, m0, kk, srow, scg, &As[srow][scg]);
        stage_f32(W, N, K, K, n0, kk, srow, scg, &Bs[srow][scg]);
        __syncthreads();
        bf16x8 af[4], bf[4];
        #pragma unroll
        for (int i = 0; i < 4; i++)
            af[i] = *reinterpret_cast<const bf16x8*>(&As[wr*64 + i*16 + ll][lg*8]);
        #pragma unroll
        for (int j = 0; j < 4; j++)
            bf[j] = *reinterpret_cast<const bf16x8*>(&Bs[wc*64 + j*16 + ll][lg*8]);
        #pragma unroll
        for (int i = 0; i < 4; i++)
            #pragma unroll
            for (int j = 0; j < 4; j++)
                acc[i][j] = __builtin_amdgcn_mfma_f32_16x16x32_bf16(af[i], bf[j], acc[i][j], 0, 0, 0);
        __syncthreads();
    }

    float bv[4];
    #pragma unroll
    for (int j = 0; j < 4; j++) {
        int n = n0 + wc*64 + j*16 + ll;
        bv[j] = (n < N) ? bias[n] : 0.f;
    }
    #pragma unroll
    for (int i = 0; i < 4; i++) {
        #pragma unroll
        for (int r = 0; r < 4; r++) {
            int m = m0 + wr*64 + i*16 + lg*4 + r;
            if (m >= M) continue;
            #pragma unroll
            for (int j = 0; j < 4; j++) {
                int n = n0 + wc*64 + j*16 + ll;
                if (n >= N) continue;
                float v = acc[i][j][r] + bv[j];
                if (RELU) v = fmaxf(v, 0.f);
                v *= scale;
                C[(size_t)m * N + n] = v;
                if (DUAL) CbL[(size_t)m * N + n] = f2bf(v);
            }
        }
    }
}

// ---------------- bf16 MFMA GEMM with global_load_lds staging --------------
template<int RELU, int BF16OUT, int QSCALE, int SPLITK, int HEADS, int VTOUT>
__global__ __launch_bounds__(256) void gemm_async(
    const u16* __restrict__ A, const u16* __restrict__ W,
    const float* __restrict__ bias, void* __restrict__ Cv, float* __restrict__ C1,
    u16* __restrict__ vtp, int M, int N, int K, int lda, float scale)
{
    __shared__ u16 As[4096];   // [128][32]
    __shared__ u16 Bs[4096];
    int t = threadIdx.x;
    int w = t >> 6, l = t & 63;
    int ll = l & 15, lg = l >> 4;
    int wr = w >> 1, wc = w & 1;
    int m0 = blockIdx.x * 128, n0 = blockIdx.y * 128;
    int srow = l >> 2;
    int skg  = (l & 3) * 8;
    int kz = SPLITK ? blockIdx.z : 0;
    int khalf = SPLITK ? (K >> 1) : K;
    int kbeg = kz * khalf;

    const u16* pa0 = A + (size_t)min(m0 + w * 16 + srow, M - 1) * lda + skg;
    const u16* pa1 = A + (size_t)min(m0 + 64 + w * 16 + srow, M - 1) * lda + skg;
    const u16* pb0 = W + (size_t)min(n0 + w * 16 + srow, N - 1) * K + skg;
    const u16* pb1 = W + (size_t)min(n0 + 64 + w * 16 + srow, N - 1) * K + skg;
    u16* la0 = &As[(w * 16) * 32];
    u16* la1 = &As[(64 + w * 16) * 32];
    u16* lb0 = &Bs[(w * 16) * 32];
    u16* lb1 = &Bs[(64 + w * 16) * 32];

    f32x4 acc[4][4];
    #pragma unroll
    for (int i = 0; i < 4; i++)
        #pragma unroll
        for (int j = 0; j < 4; j++) acc[i][j] = (f32x4){0.f, 0.f, 0.f, 0.f};

    for (int kk = kbeg; kk < kbeg + khalf; kk += 32) {
        async_ld16(pa0 + kk, la0);
        async_ld16(pa1 + kk, la1);
        async_ld16(pb0 + kk, lb0);
        async_ld16(pb1 + kk, lb1);
        __syncthreads();
        bf16x8 af[4], bf[4];
        #pragma unroll
        for (int i = 0; i < 4; i++)
            af[i] = *reinterpret_cast<const bf16x8*>(&As[(wr*64 + i*16 + ll) * 32 + lg*8]);
        #pragma unroll
        for (int j = 0; j < 4; j++)
            bf[j] = *reinterpret_cast<const bf16x8*>(&Bs[(wc*64 + j*16 + ll) * 32 + lg*8]);
        #pragma unroll
        for (int i = 0; i < 4; i++)
            #pragma unroll
            for (int j = 0; j < 4; j++)
                acc[i][j] = __builtin_amdgcn_mfma_f32_16x16x32_bf16(af[i], bf[j], acc[i][j], 0, 0, 0);
        __syncthreads();
    }

    float bv[4];
    #pragma unroll
    for (int j = 0; j < 4; j++) {
        int n = n0 + wc*64 + j*16 + ll;
        bv[j] = (n < N && (!SPLITK || kz == 0)) ? bias[n] : 0.f;
    }
    #pragma unroll
    for (int i = 0; i < 4; i++) {
        if (VTOUT) {
            #pragma unroll
            for (int j = 0; j < 4; j++) {
                int n = n0 + wc*64 + j*16 + ll;
                int mb = m0 + wr*64 + i*16 + lg*4;
                if (n >= 1024) {
                    if (mb < T_TOK) {
                        ushort4 o;
                        o.x = f2bf(acc[i][j][0] + bv[j]);
                        o.y = f2bf(acc[i][j][1] + bv[j]);
                        o.z = f2bf(acc[i][j][2] + bv[j]);
                        o.w = f2bf(acc[i][j][3] + bv[j]);
                        *reinterpret_cast<ushort4*>(vtp + (size_t)(n - 1024) * VT_S + mb) = o;
                    }
                } else {
                    #pragma unroll
                    for (int r = 0; r < 4; r++) {
                        int mm = mb + r;
                        if (mm >= M) continue;
                        float v = acc[i][j][r] + bv[j];
                        if (n < 512) v *= QK_SCALE;
                        ((u16*)Cv)[(size_t)mm * QKS + n] = f2bf(v);
                    }
                }
            }
        } else {
            #pragma unroll
            for (int r = 0; r < 4; r++) {
                int m = m0 + wr*64 + i*16 + lg*4 + r;
                if (m >= M) continue;
                #pragma unroll
                for (int j = 0; j < 4; j++) {
                    int n = n0 + wc*64 + j*16 + ll;
                    if (n >= N) continue;
                    float v = acc[i][j][r] + bv[j];
                    if (RELU) v = fmaxf(v, 0.f);
                    v *= scale;
                    if (QSCALE && n < 512) v *= QK_SCALE;
                    if (HEADS) {
                        float* o = (float*)Cv;
                        if (n < 121)       o[(size_t)m * 121 + n] = v;
                        else if (n < 1452) (o + 435600)[(size_t)m * 1331 + (n - 121)] = v;
                        else               (o + 5227200)[(size_t)m * 10 + (n - 1452)] = v;
                    } else if (SPLITK && kz == 1) {
                        C1[(size_t)m * N + n] = v;
                    } else if (BF16OUT) {
                        ((u16*)Cv)[(size_t)m * N + n] = f2bf(v);
                    } else {
                        ((float*)Cv)[(size_t)m * N + n] = v;
                    }
                }
            }
        }
    }
}

// ---------------- MFMA flash attention: 32 q/wave, swapped QK^T ------------
// grid 3648 = 57 pairs x 8 z x 8 heads; h = bid&7 pins head->XCD.
// z-striding over VISIBLE-tile rank (not absolute kt) -> balanced per-z work.
__global__ __launch_bounds__(64) void attn_mfma_kernel(
    const u16* __restrict__ qkvb, const u16* __restrict__ vt,
    u16* __restrict__ Op0, u16* __restrict__ Op1, float* __restrict__ mlpart)
{
    __shared__ u16 plds[2][16][66];
    int l = threadIdx.x;
    int lg = l >> 4, ll = l & 15;
    int bid = blockIdx.x;
    int h = bid & 7;
    int rest = bid >> 3;      // 0..455
    int z = rest / 57;        // 0..7
    int pr = rest - z * 57;   // 0..56

    #pragma unroll 1
    for (int tpart = 0; tpart < 2; tpart++) {
        if (tpart == 1 && pr == 56) break;
        int rank = (tpart == 0) ? pr : 112 - pr;
        int q0 = (112 - rank) * 32;

        bf16x8 qf0[2], qf1[2];
        int sql[2];
        bool qok[2];
        #pragma unroll
        for (int b = 0; b < 2; b++) {
            int qa = q0 + b * 16 + ll;
            qok[b] = qa < T_TOK;
            int qac = min(qa, T_TOK - 1);
            const u16* qrow = qkvb + (size_t)qac * QKS + h * HD + lg * 8;
            qf0[b] = *reinterpret_cast<const bf16x8*>(qrow);
            qf1[b] = *reinterpret_cast<const bf16x8*>(qrow + 32);
            sql[b] = step_of(qac);
        }
        int sl = max(sql[0], sql[1]), s2 = min(sql[0], sql[1]);
        #pragma unroll
        for (int off = 1; off < 16; off <<= 1) {
            sl = max(sl, __shfl_xor(sl, off));
            s2 = min(s2, __shfl_xor(s2, off));
        }
        int smax = sl, smin = s2;
        int limp[2], limb[2], limc[2];
        #pragma unroll
        for (int b = 0; b < 2; b++) {
            limp[b] = sql[b] * 10 + 9;
            limb[b] = 3000 + sql[b];
            limc[b] = 3300 + sql[b];
        }

        f32x4 oacc[2][4];
        #pragma unroll
        for (int b = 0; b < 2; b++)
            #pragma unroll
            for (int i = 0; i < 4; i++) oacc[b][i] = (f32x4){0.f, 0.f, 0.f, 0.f};
        float m[2] = {-INFINITY, -INFINITY};
        float ls[2] = {0.f, 0.f};

        int cz = 0;   // visible-tile rank mod KSPLIT
        #pragma unroll 1
        for (int kt = 0; kt < NKT; kt++) {
            int kbase = kt * 64;
            int mn, mx;
            tile_minmax(kbase, mn, mx);
            if (mn > smax) continue;
            bool mine = (cz == z);
            cz = (cz + 1) & 7;
            if (!mine) continue;
            bool needmask = (mx > smin) || (kbase + 64 > T_TOK);

            bf16x8 kf0[4], kf1[4];
            #pragma unroll
            for (int f = 0; f < 4; f++) {
                int keyc = min(kbase + f * 16 + ll, T_TOK - 1);
                const u16* kr = qkvb + (size_t)keyc * QKS + 512 + h * HD + lg * 8;
                kf0[f] = *reinterpret_cast<const bf16x8*>(kr);
                kf1[f] = *reinterpret_cast<const bf16x8*>(kr + 32);
            }
            bf16x8 vf0[4], vf1[4];
            #pragma unroll
            for (int i = 0; i < 4; i++) {
                const u16* vr = vt + (size_t)(h * HD + i * 16 + ll) * VT_S + kbase + lg * 8;
                vf0[i] = *reinterpret_cast<const bf16x8*>(vr);
                vf1[i] = *reinterpret_cast<const bf16x8*>(vr + 32);
            }

            f32x4 sfr[2][4];
            __builtin_amdgcn_s_setprio(1);
            #pragma unroll
            for (int f = 0; f < 4; f++) {
                #pragma unroll
                for (int b = 0; b < 2; b++) {
                    f32x4 acc = (f32x4){0.f, 0.f, 0.f, 0.f};
                    acc = __builtin_amdgcn_mfma_f32_16x16x32_bf16(kf0[f], qf0[b], acc, 0, 0, 0);
                    acc = __builtin_amdgcn_mfma_f32_16x16x32_bf16(kf1[f], qf1[b], acc, 0, 0, 0);
                    sfr[b][f] = acc;
                }
            }
            __builtin_amdgcn_s_setprio(0);

            float rmax[2] = {-INFINITY, -INFINITY};
            if (!needmask) {
                #pragma unroll
                for (int f = 0; f < 4; f++)
                    #pragma unroll
                    for (int b = 0; b < 2; b++)
                        #pragma unroll
                        for (int r = 0; r < 4; r++) rmax[b] = fmaxf(rmax[b], sfr[b][f][r]);
            } else {
                #pragma unroll
                for (int f = 0; f < 4; f++)
                    #pragma unroll
                    for (int r = 0; r < 4; r++) {
                        int key = kbase + f * 16 + lg * 4 + r;
                        #pragma unroll
                        for (int b = 0; b < 2; b++) {
                            int lim = (key < 3000) ? limp[b] : ((key < 3300) ? limb[b] : limc[b]);
                            float v = sfr[b][f][r];
                            v = (key <= lim) ? v : -INFINITY;
                            sfr[b][f][r] = v;
                            rmax[b] = fmaxf(rmax[b], v);
                        }
                    }
            }
            if (!qok[0]) rmax[0] = -INFINITY;
            if (!qok[1]) rmax[1] = -INFINITY;
            #pragma unroll
            for (int b = 0; b < 2; b++) {
                rmax[b] = fmaxf(rmax[b], __shfl_xor(rmax[b], 16));
                rmax[b] = fmaxf(rmax[b], __shfl_xor(rmax[b], 32));
            }
            bool upd = (rmax[0] > m[0] + 8.f) || (rmax[1] > m[1] + 8.f);
            if (__any(upd)) {
                #pragma unroll
                for (int b = 0; b < 2; b++) {
                    float mn2 = fmaxf(m[b], rmax[b]);
                    float c = (m[b] == -INFINITY) ? 0.f : exp2f(m[b] - mn2);
                    m[b] = mn2;
                    ls[b] *= c;
                    f32x4 cv;
                    cv[0] = __shfl(c, lg * 4 + 0);
                    cv[1] = __shfl(c, lg * 4 + 1);
                    cv[2] = __shfl(c, lg * 4 + 2);
                    cv[3] = __shfl(c, lg * 4 + 3);
                    #pragma unroll
                    for (int i = 0; i < 4; i++) {
                        oacc[b][i][0] *= cv[0]; oacc[b][i][1] *= cv[1];
                        oacc[b][i][2] *= cv[2]; oacc[b][i][3] *= cv[3];
                    }
                }
            }
            if (!needmask) {
                #pragma unroll
                for (int b = 0; b < 2; b++)
                    #pragma unroll
                    for (int f = 0; f < 4; f++) {
                        float p0 = exp2f(sfr[b][f][0] - m[b]);
                        float p1 = exp2f(sfr[b][f][1] - m[b]);
                        float p2 = exp2f(sfr[b][f][2] - m[b]);
                        float p3 = exp2f(sfr[b][f][3] - m[b]);
                        ls[b] += (p0 + p1) + (p2 + p3);
                        *reinterpret_cast<u32*>(&plds[b][ll][f * 16 + lg * 4])     = cvt_pk_bf16(p0, p1);
                        *reinterpret_cast<u32*>(&plds[b][ll][f * 16 + lg * 4 + 2]) = cvt_pk_bf16(p2, p3);
                    }
            } else {
                #pragma unroll
                for (int b = 0; b < 2; b++)
                    #pragma unroll
                    for (int f = 0; f < 4; f++) {
                        float sv0 = sfr[b][f][0], sv1 = sfr[b][f][1];
                        float sv2 = sfr[b][f][2], sv3 = sfr[b][f][3];
                        float p0 = (sv0 == -INFINITY) ? 0.f : exp2f(sv0 - m[b]);
                        float p1 = (sv1 == -INFINITY) ? 0.f : exp2f(sv1 - m[b]);
                        float p2 = (sv2 == -INFINITY) ? 0.f : exp2f(sv2 - m[b]);
                        float p3 = (sv3 == -INFINITY) ? 0.f : exp2f(sv3 - m[b]);
                        ls[b] += (p0 + p1) + (p2 + p3);
                        *reinterpret_cast<u32*>(&plds[b][ll][f * 16 + lg * 4])     = cvt_pk_bf16(p0, p1);
                        *reinterpret_cast<u32*>(&plds[b][ll][f * 16 + lg * 4 + 2]) = cvt_pk_bf16(p2, p3);
                    }
            }
            __builtin_amdgcn_s_setprio(1);
            #pragma unroll
            for (int b = 0; b < 2; b++) {
                bf16x8 pf0 = *reinterpret_cast<const bf16x8*>(&plds[b][ll][lg * 8]);
                #pragma unroll
                for (int i = 0; i < 4; i++)
                    oacc[b][i] = __builtin_amdgcn_mfma_f32_16x16x32_bf16(pf0, vf0[i], oacc[b][i], 0, 0, 0);
                bf16x8 pf1 = *reinterpret_cast<const bf16x8*>(&plds[b][ll][32 + lg * 8]);
                #pragma unroll
                for (int i = 0; i < 4; i++)
                    oacc[b][i] = __builtin_amdgcn_mfma_f32_16x16x32_bf16(pf1, vf1[i], oacc[b][i], 0, 0, 0);
            }
            __builtin_amdgcn_s_setprio(0);
        }

        #pragma unroll
        for (int b = 0; b < 2; b++) {
            ls[b] += __shfl_xor(ls[b], 16);
            ls[b] += __shfl_xor(ls[b], 32);
        }
        u16* Ob = (z < 5) ? (Op0 + (size_t)z * ZSLICE) : (Op1 + (size_t)(z - 5) * ZSLICE);
        #pragma unroll
        for (int b = 0; b < 2; b++)
            #pragma unroll
            for (int r = 0; r < 4; r++) {
                int q = q0 + b * 16 + lg * 4 + r;
                if (q >= T_TOK) continue;
                size_t ob = ((size_t)h * 3600 + q) * 64;
                #pragma unroll
                for (int i = 0; i < 4; i++)
                    Ob[ob + i * 16 + ll] = f2bf(oacc[b][i][r]);
            }
        if (lg == 0) {
            #pragma unroll
            for (int b = 0; b < 2; b++) {
                int qa = q0 + b * 16 + ll;
                if (qa < T_TOK) {
                    size_t mi = ((size_t)(z * 8 + h) * 3600 + qa) * 2;
                    mlpart[mi]     = m[b];
                    mlpart[mi + 1] = ls[b];
                }
            }
        }
    }
}

// ---------------- merge KSPLIT partials -> obb (vectorized) ----------------
__global__ __launch_bounds__(256) void attn_merge_kernel(
    const u16* __restrict__ Op0, const u16* __restrict__ Op1,
    const float* __restrict__ mlpart, u16* __restrict__ obb)
{
    int t = threadIdx.x;
    int h = blockIdx.y;
    int q = blockIdx.x * 64 + (t >> 2);
    if (q >= T_TOK) return;
    int dg = (t & 3) * 16;
    float mz[KSPLIT], lz[KSPLIT];
    #pragma unroll
    for (int zz = 0; zz < KSPLIT; zz++) {
        size_t mi = ((size_t)(zz * 8 + h) * 3600 + q) * 2;
        mz[zz] = mlpart[mi];
        lz[zz] = mlpart[mi + 1];
    }
    float M = -INFINITY;
    #pragma unroll
    for (int zz = 0; zz < KSPLIT; zz++) if (lz[zz] > 0.f) M = fmaxf(M, mz[zz]);
    float wz[KSPLIT], den = 0.f;
    #pragma unroll
    for (int zz = 0; zz < KSPLIT; zz++) {
        wz[zz] = (lz[zz] > 0.f) ? exp2f(mz[zz] - M) : 0.f;
        den += wz[zz] * lz[zz];
    }
    float inv = (den > 0.f) ? 1.f / den : 0.f;
    size_t qoff = ((size_t)h * 3600 + q) * 64 + dg;
    float acc[16];
    #pragma unroll
    for (int e = 0; e < 16; e++) acc[e] = 0.f;
    #pragma unroll
    for (int zz = 0; zz < KSPLIT; zz++) {
        const u16* Ob = (zz < 5) ? (Op0 + (size_t)zz * ZSLICE) : (Op1 + (size_t)(zz - 5) * ZSLICE);
        bf16x8 v0 = *reinterpret_cast<const bf16x8*>(Ob + qoff);
        bf16x8 v1 = *reinterpret_cast<const bf16x8*>(Ob + qoff + 8);
        float w = wz[zz];
        #pragma unroll
        for (int e = 0; e < 8; e++) {
            acc[e]     += bf2f((u16)v0[e]) * w;
            acc[8 + e] += bf2f((u16)v1[e]) * w;
        }
    }
    u16 o16[16];
    #pragma unroll
    for (int e = 0; e < 16; e++) o16[e] = f2bf(acc[e] * inv);
    u16* op = obb + (size_t)q * D_ + h * HD + dg;
    *reinterpret_cast<bf16x8*>(op)     = *reinterpret_cast<const bf16x8*>(&o16[0]);
    *reinterpret_cast<bf16x8*>(op + 8) = *reinterpret_cast<const bf16x8*>(&o16[8]);
}

// ---------------- residual add (two partials) + LayerNorm (float4) --------
__global__ __launch_bounds__(128) void add_ln3_kernel(
    float* __restrict__ x, const float* __restrict__ r1, const float* __restrict__ r2,
    const float* __restrict__ g, const float* __restrict__ b,
    u16* __restrict__ xb)
{
    int row = blockIdx.x, t = threadIdx.x;   // 128 threads, 4 elems each
    size_t base = (size_t)row * D_ + t * 4;
    float4 xv = *reinterpret_cast<const float4*>(&x[base]);
    float4 a1 = *reinterpret_cast<const float4*>(&r1[base]);
    float4 a2 = *reinterpret_cast<const float4*>(&r2[base]);
    float v0 = xv.x + a1.x + a2.x;
    float v1 = xv.y + a1.y + a2.y;
    float v2 = xv.z + a1.z + a2.z;
    float v3 = xv.w + a1.w + a2.w;
    float s = (v0 + v1) + (v2 + v3);
    float ss = (v0 * v0 + v1 * v1) + (v2 * v2 + v3 * v3);
    #pragma unroll
    for (int off = 32; off > 0; off >>= 1) {
        s  += __shfl_xor(s, off);
        ss += __shfl_xor(ss, off);
    }
    __shared__ float rs[2], rss[2];
    int w = t >> 6;
    if ((t & 63) == 0) { rs[w] = s; rss[w] = ss; }
    __syncthreads();
    s  = rs[0] + rs[1];
    ss = rss[0] + rss[1];
    float mean = s * (1.f / 512.f);
    float var = ss * (1.f / 512.f) - mean * mean;
    float rstd = rsqrtf(var + 1e-5f);
    float4 gv = *reinterpret_cast<const float4*>(&g[t * 4]);
    float4 bv = *reinterpret_cast<const float4*>(&b[t * 4]);
    float o0 = (v0 - mean) * rstd * gv.x + bv.x;
    float o1 = (v1 - mean) * rstd * gv.y + bv.y;
    float o2 = (v2 - mean) * rstd * gv.z + bv.z;
    float o3 = (v3 - mean) * rstd * gv.w + bv.w;
    *reinterpret_cast<float4*>(&x[base]) = make_float4(o0, o1, o2, o3);
    ushort4 ob;
    ob.x = f2bf(o0); ob.y = f2bf(o1); ob.z = f2bf(o2); ob.w = f2bf(o3);
    *reinterpret_cast<ushort4*>(&xb[base]) = ob;
}

// ---------------------------------------------------------------------------
extern "C" void kernel_launch(void* const* d_in, const int* in_sizes, int n_in,
                              void* d_out, int out_size, void* d_ws, size_t ws_size,
                              hipStream_t stream)
{
    const float* player_xs = (const float*)d_in[0];
    const float* player_ys = (const float*)d_in[1];
    const float* player_hs = (const float*)d_in[2];
    const float* ball_xs   = (const float*)d_in[3];
    const float* ball_ys   = (const float*)d_in[4];
    const float* ball_zs   = (const float*)d_in[5];
    const float* emb_table = (const float*)d_in[6];
    const float* ball_emb  = (const float*)d_in[7];
    const float* cls_emb   = (const float*)d_in[8];
    const float* pW0 = (const float*)d_in[9];   const float* pb0 = (const float*)d_in[10];
    const float* pW1 = (const float*)d_in[11];  const float* pb1 = (const float*)d_in[12];
    const float* pW2 = (const float*)d_in[13];  const float* pb2 = (const float*)d_in[14];
    const float* bW0 = (const float*)d_in[15];  const float* bb0 = (const float*)d_in[16];
    const float* bW1 = (const float*)d_in[17];  const float* bb1 = (const float*)d_in[18];
    const float* bW2 = (const float*)d_in[19];  const float* bb2 = (const float*)d_in[20];
    const float* Wqkv = (const float*)d_in[21]; const float* bqkv = (const float*)d_in[22];
    const float* Wo  = (const float*)d_in[23];  const float* bo  = (const float*)d_in[24];
    const float* W1f = (const float*)d_in[25];  const float* b1f = (const float*)d_in[26];
    const float* W2f = (const float*)d_in[27];  const float* b2f = (const float*)d_in[28];
    const float* g1  = (const float*)d_in[29];  const float* be1 = (const float*)d_in[30];
    const float* g2  = (const float*)d_in[31];  const float* be2 = (const float*)d_in[32];
    const float* cpW = (const float*)d_in[33];  const float* cpb = (const float*)d_in[34];
    const float* cbW = (const float*)d_in[35];  const float* cbb = (const float*)d_in[36];
    const float* csW = (const float*)d_in[37];  const float* csb = (const float*)d_in[38];
    const int* pidx = (const int*)d_in[39];

    // workspace (51.6 MB): x | big | obr | tmp2
    float* x    = (float*)d_ws;            // 1,843,200 f32
    float* big  = x + 1843200;             // 7,372,800 f32
    float* obr  = big + 7372800;           // 1,843,200 f32
    float* tmp2 = obr + 1843200;           // 1,843,200 f32
    u16*   qkvb   = (u16*)big;             // [3600][1024] bf16 (Q|K, compact)
    u16*   Op0    = (u16*)(big + 2764800); // z-slices 0-4
    u16*   wbh    = (u16*)(big + 6681600); // head weights bf16
    float* bhead  = big + 7100000;         // packed head bias
    u16*   ff1b   = (u16*)big;             // [3600][2048] bf16 (FF phase)
    float* r2buf  = big + 4000000;         // split-K second partial
    u16*   obb    = (u16*)obr;             // [3600][512] bf16
    u16*   xb     = (u16*)(obr + 921600);  // [3600][512] bf16
    u16*   vt     = (u16*)tmp2;            // [512][3648] bf16
    float* mlpart = tmp2 + 1000000;        // [8][8][3600][2] f32
    float* out = (float*)d_out;
    u16* wpack  = (u16*)d_out;
    u16* wqkv_b = wpack;                   // 1536*512
    u16* wo_b   = wpack + 786432;          // 512*512
    u16* w1f_b  = wpack + 1048576;         // 2048*512
    u16* w2f_b  = wpack + 2097152;         // 512*2048
    u16* Op1    = wpack + 3145728;         // z-slices 5-7
    float* IN = big;                       // 3600*24
    float* h0 = big + 131072;              // 3600*128
    float* h1 = big + 131072 + 460800;     // 3600*256

    gather_kernel<<<15, 256, 0, stream>>>(
        player_xs, player_ys, player_hs, ball_xs, ball_ys, ball_zs,
        emb_table, ball_emb, cls_emb, pidx, IN, x, xb);

    gemm_tok<1,0><<<dim3(24, 1, 2), 256, 0, stream>>>(
        IN, pW0, pb0, h0, IN + 3000*24, bW0, bb0, h0 + 3000*128, nullptr,
        3000, 300, 128, 23, 24, 1.f);
    gemm_tok<1,0><<<dim3(24, 2, 2), 256, 0, stream>>>(
        h0, pW1, pb1, h1, h0 + 3000*128, bW1, bb1, h1 + 3000*256, nullptr,
        3000, 300, 256, 128, 128, 1.f);
    gemm_tok<0,1><<<dim3(24, 4, 2), 256, 0, stream>>>(
        h1, pW2, pb2, x, h1 + 3000*256, bW2, bb2, x + 3000*512, xb,
        3000, 300, 512, 256, 256, SQRT512);

    for (int l = 0; l < 4; l++) {
        const float* Wqkv_l = Wqkv + (size_t)l * 1536 * 512;
        const float* bqkv_l = bqkv + (size_t)l * 1536;
        const float* bo_l   = bo   + (size_t)l * 512;
        const float* Wo_l   = Wo   + (size_t)l * 512 * 512;
        const float* W1f_l  = W1f  + (size_t)l * 2048 * 512;
        const float* b1f_l  = b1f  + (size_t)l * 2048;
        const float* W2f_l  = W2f  + (size_t)l * 512 * 2048;
        const float* b2f_l  = b2f  + (size_t)l * 512;

        w2b4_kernel<<<1024, 256, 0, stream>>>(Wqkv_l, Wo_l, W1f_l, W2f_l, wpack, vt);
        gemm_async<0,1,1,0,0,1><<<dim3(29, 12), 256, 0, stream>>>(xb, wqkv_b, bqkv_l, qkvb, nullptr, vt, 3600, 1536, 512, 512, 1.f);
        attn_mfma_kernel<<<57 * 8 * 8, 64, 0, stream>>>(qkvb, vt, Op0, Op1, mlpart);
        attn_merge_kernel<<<dim3(57, 8), 256, 0, stream>>>(Op0, Op1, mlpart, obb);
        gemm_async<0,0,0,1,0,0><<<dim3(29, 4, 2), 256, 0, stream>>>(obb, wo_b, bo_l, tmp2, r2buf, nullptr, 3600, 512, 512, 512, 1.f);
        add_ln3_kernel<<<3600, 128, 0, stream>>>(x, tmp2, r2buf, g1 + (size_t)l * 512, be1 + (size_t)l * 512, xb);
        gemm_async<1,1,0,0,0,0><<<dim3(29, 16), 256, 0, stream>>>(xb, w1f_b, b1f_l, ff1b, nullptr, nullptr, 3600, 2048, 512, 512, 1.f);
        gemm_async<0,0,0,1,0,0><<<dim3(29, 4, 2), 256, 0, stream>>>(ff1b, w2f_b, b2f_l, tmp2, r2buf, nullptr, 3600, 512, 2048, 2048, 1.f);
        add_ln3_kernel<<<3600, 128, 0, stream>>>(x, tmp2, r2buf, g2 + (size_t)l * 512, be2 + (size_t)l * 512, xb);
    }

    w2bh_kernel<<<732, 256, 0, stream>>>(cpW, cbW, csW, cpb, cbb, csb, wbh, bhead);
    gemm_async<0,0,0,0,1,0><<<dim3(29, 12), 256, 0, stream>>>(xb, wbh, bhead, out, nullptr, nullptr, 3600, 1462, 512, 512, 1.f);
}

// Round 20
// 893.198 us; speedup vs baseline: 1.0767x; 1.0767x over previous
//
#include <hip/hip_runtime.h>
#include <hip/hip_bf16.h>

typedef unsigned short u16;
typedef unsigned int u32;
typedef __attribute__((ext_vector_type(8))) short bf16x8;
typedef __attribute__((ext_vector_type(4))) float f32x4;

#define T_TOK 3600
#define D_    512
#define H_    8
#define HD    64
#define NKT   57
#define VT_S  3648
#define KSPLIT 8
#define ZSLICE 1843200  // u16 per z-slice: 8*3600*64
#define QKS   1024      // qkvb row stride (Q|K only)
#define SQRT512 22.627416997969522f
#define QK_SCALE 0.18033688011112042f // 0.125 * log2(e)

__device__ __forceinline__ u16 f2bf(float f) {
    unsigned int x = __float_as_uint(f);
    unsigned int lsb = (x >> 16) & 1;
    return (u16)((x + 0x7fffu + lsb) >> 16);
}
__device__ __forceinline__ float bf2f(u16 u) {
    return __uint_as_float(((unsigned int)u) << 16);
}
__device__ __forceinline__ u32 cvt_pk_bf16(float a, float b) {
    u32 r;
    asm("v_cvt_pk_bf16_f32 %0, %1, %2" : "=v"(r) : "v"(a), "v"(b));
    return r;
}
__device__ __forceinline__ void async_ld16(const void* g, void* l) {
    __builtin_amdgcn_global_load_lds(
        (const __attribute__((address_space(1))) void*)g,
        (__attribute__((address_space(3))) void*)l, 16, 0, 0);
}
__device__ __forceinline__ int step_of(int i) {
    return (i < 3000) ? (i / 10) : ((i < 3300) ? (i - 3000) : (i - 3300));
}
__device__ __forceinline__ void tile_minmax(int kbase, int& mn, int& mx) {
    int a = kbase, b = min(kbase + 63, T_TOK - 1);
    mn = 0x7fffffff; mx = -1;
    if (a < 3000)              { mn = min(mn, a / 10);              mx = max(mx, min(b, 2999) / 10); }
    if (b >= 3000 && a < 3300) { mn = min(mn, max(a, 3000) - 3000); mx = max(mx, min(b, 3299) - 3000); }
    if (b >= 3300)             { mn = min(mn, max(a, 3300) - 3300); mx = max(mx, b - 3300); }
}

// ---------------- gather: IN[3600][24] + cls rows of x and xb --------------
__global__ __launch_bounds__(256) void gather_kernel(
    const float* __restrict__ pxs, const float* __restrict__ pys, const float* __restrict__ phs,
    const float* __restrict__ bxs, const float* __restrict__ bys, const float* __restrict__ bzs,
    const float* __restrict__ emb_table, const float* __restrict__ ball_emb,
    const float* __restrict__ cls_emb, const int* __restrict__ pidx,
    float* __restrict__ IN, float* __restrict__ x, u16* __restrict__ xb)
{
    int g = blockIdx.x * 256 + threadIdx.x;
    if (g < 3300) {
        float* row = IN + g * 24;
        if (g < 3000) {
            int id = pidx[g];
            #pragma unroll
            for (int e = 0; e < 20; e++) row[e] = emb_table[id * 20 + e];
            row[20] = pxs[g]; row[21] = pys[g]; row[22] = phs[g];
        } else {
            int b = g - 3000;
            #pragma unroll
            for (int e = 0; e < 20; e++) row[e] = ball_emb[e];
            row[20] = bxs[b]; row[21] = bys[b]; row[22] = bzs[b];
        }
        row[23] = 0.f;
    }
    for (int i = g; i < 300 * 512; i += 3840) {
        float v = cls_emb[i & 511];
        x[3300 * 512 + i] = v;
        xb[3300 * 512 + i] = f2bf(v);
    }
}

// ---------------- per-layer weight convert + vt-pad zero -------------------
__global__ __launch_bounds__(256) void w2b4_kernel(
    const float* __restrict__ s0, const float* __restrict__ s1,
    const float* __restrict__ s2, const float* __restrict__ s3,
    u16* __restrict__ dst, u16* __restrict__ vt)
{
    int stride = gridDim.x * 256;
    for (int i = blockIdx.x * 256 + threadIdx.x; i < 786432; i += stride) {
        const float4* src;
        int j = i;
        if (j < 196608)      { src = (const float4*)s0; }
        else if (j < 262144) { src = (const float4*)s1; j -= 196608; }
        else if (j < 524288) { src = (const float4*)s2; j -= 262144; }
        else                 { src = (const float4*)s3; j -= 524288; }
        float4 v = src[j];
        ushort4 o;
        o.x = f2bf(v.x); o.y = f2bf(v.y); o.z = f2bf(v.z); o.w = f2bf(v.w);
        reinterpret_cast<ushort4*>(dst)[i] = o;
    }
    // zero vt's pad tokens [3600,3648) on all 512 rows
    for (int i = blockIdx.x * 256 + threadIdx.x; i < 512 * 64; i += stride) {
        int row = i >> 6, c = i & 63;
        if (c < 48) vt[(size_t)row * VT_S + 3600 + c] = 0;
    }
}

// ---------------- head-weight + bias pack ----------------------------------
__global__ __launch_bounds__(256) void w2bh_kernel(
    const float* __restrict__ cp, const float* __restrict__ cb,
    const float* __restrict__ cs, const float* __restrict__ bp,
    const float* __restrict__ bb, const float* __restrict__ bs,
    u16* __restrict__ dst, float* __restrict__ bias)
{
    int stride = gridDim.x * 256;
    for (int i = blockIdx.x * 256 + threadIdx.x; i < 187136; i += stride) {
        const float4* src;
        int j = i;
        if (j < 15488)       { src = (const float4*)cp; }
        else if (j < 185856) { src = (const float4*)cb; j -= 15488; }
        else                 { src = (const float4*)cs; j -= 185856; }
        float4 v = src[j];
        ushort4 o;
        o.x = f2bf(v.x); o.y = f2bf(v.y); o.z = f2bf(v.z); o.w = f2bf(v.w);
        reinterpret_cast<ushort4*>(dst)[i] = o;
    }
    int g = blockIdx.x * 256 + threadIdx.x;
    if (g < 1462)
        bias[g] = (g < 121) ? bp[g] : (g < 1452) ? bb[g - 121] : bs[g - 1452];
}

// ---------------- fp32-input token GEMM: player(z=0) / ball(z=1) ----------
__device__ __forceinline__ void stage_f32(
    const float* __restrict__ src, int nrows, int K, int lda,
    int r0, int kk, int srow, int scg, u16* dst)
{
    u16 tmp[16];
    int rr = r0 + srow;
    if (rr < nrows) {
        if (((lda & 3) == 0) && (kk + scg + 16 <= K)) {
            const float4* p = reinterpret_cast<const float4*>(src + (size_t)rr * lda + kk + scg);
            #pragma unroll
            for (int q = 0; q < 4; q++) {
                float4 v = p[q];
                tmp[q*4+0] = f2bf(v.x); tmp[q*4+1] = f2bf(v.y);
                tmp[q*4+2] = f2bf(v.z); tmp[q*4+3] = f2bf(v.w);
            }
        } else {
            #pragma unroll
            for (int e = 0; e < 16; e++) {
                int kc = kk + scg + e;
                tmp[e] = (kc < K) ? f2bf(src[(size_t)rr * lda + kc]) : (u16)0;
            }
        }
    } else {
        #pragma unroll
        for (int e = 0; e < 16; e++) tmp[e] = 0;
    }
    *reinterpret_cast<bf16x8*>(dst)     = *reinterpret_cast<const bf16x8*>(&tmp[0]);
    *reinterpret_cast<bf16x8*>(dst + 8) = *reinterpret_cast<const bf16x8*>(&tmp[8]);
}

template<int RELU, int DUAL>
__global__ __launch_bounds__(256) void gemm_tok(
    const float* __restrict__ A0, const float* __restrict__ W0p,
    const float* __restrict__ b0p, float* __restrict__ C0,
    const float* __restrict__ A1, const float* __restrict__ W1p,
    const float* __restrict__ b1p, float* __restrict__ C1,
    u16* __restrict__ Cb,
    int M0, int M1, int N, int K, int lda, float scale)
{
    int zz = blockIdx.z;
    int M = zz ? M1 : M0;
    int m0 = blockIdx.x * 128;
    if (m0 >= M) return;
    const float* A = zz ? A1 : A0;
    const float* W = zz ? W1p : W0p;
    const float* bias = zz ? b1p : b0p;
    float* C = zz ? C1 : C0;
    u16* CbL = DUAL ? (zz ? Cb + (size_t)M0 * N : Cb) : nullptr;

    __shared__ u16 As[128][40];
    __shared__ u16 Bs[128][40];
    int t = threadIdx.x;
    int w = t >> 6, l = t & 63;
    int ll = l & 15, lg = l >> 4;
    int wr = w >> 1, wc = w & 1;
    int n0 = blockIdx.y * 128;
    int srow = t >> 1;
    int scg  = (t & 1) * 16;

    f32x4 acc[4][4];
    #pragma unroll
    for (int i = 0; i < 4; i++)
        #pragma unroll
        for (int j = 0; j < 4; j++) acc[i][j] = (f32x4){0.f, 0.f, 0.f, 0.f};

    for (int kk = 0; kk < K; kk += 32) {
        stage_f32(A, M, K, lda, m0, kk, srow, scg, &As[srow][scg]);
        stage_f32(W, N, K, K, n0, kk, srow, scg, &Bs[srow][scg]);
        __syncthreads();
        bf16x8 af[4], bf[4];
        #pragma unroll
        for (int i = 0; i < 4; i++)
            af[i] = *reinterpret_cast<const bf16x8*>(&As[wr*64 + i*16 + ll][lg*8]);
        #pragma unroll
        for (int j = 0; j < 4; j++)
            bf[j] = *reinterpret_cast<const bf16x8*>(&Bs[wc*64 + j*16 + ll][lg*8]);
        #pragma unroll
        for (int i = 0; i < 4; i++)
            #pragma unroll
            for (int j = 0; j < 4; j++)
                acc[i][j] = __builtin_amdgcn_mfma_f32_16x16x32_bf16(af[i], bf[j], acc[i][j], 0, 0, 0);
        __syncthreads();
    }

    float bv[4];
    #pragma unroll
    for (int j = 0; j < 4; j++) {
        int n = n0 + wc*64 + j*16 + ll;
        bv[j] = (n < N) ? bias[n] : 0.f;
    }
    #pragma unroll
    for (int i = 0; i < 4; i++) {
        #pragma unroll
        for (int r = 0; r < 4; r++) {
            int m = m0 + wr*64 + i*16 + lg*4 + r;
            if (m >= M) continue;
            #pragma unroll
            for (int j = 0; j < 4; j++) {
                int n = n0 + wc*64 + j*16 + ll;
                if (n >= N) continue;
                float v = acc[i][j][r] + bv[j];
                if (RELU) v = fmaxf(v, 0.f);
                v *= scale;
                C[(size_t)m * N + n] = v;
                if (DUAL) CbL[(size_t)m * N + n] = f2bf(v);
            }
        }
    }
}

// ---------------- bf16 MFMA GEMM with global_load_lds staging --------------
template<int RELU, int BF16OUT, int QSCALE, int SPLITK, int HEADS, int VTOUT>
__global__ __launch_bounds__(256) void gemm_async(
    const u16* __restrict__ A, const u16* __restrict__ W,
    const float* __restrict__ bias, void* __restrict__ Cv, float* __restrict__ C1,
    u16* __restrict__ vtp, int M, int N, int K, int lda, float scale)
{
    __shared__ u16 As[4096];   // [128][32]
    __shared__ u16 Bs[4096];
    int t = threadIdx.x;
    int w = t >> 6, l = t & 63;
    int ll = l & 15, lg = l >> 4;
    int wr = w >> 1, wc = w & 1;
    int m0 = blockIdx.x * 128, n0 = blockIdx.y * 128;
    int srow = l >> 2;
    int skg  = (l & 3) * 8;
    int kz = SPLITK ? blockIdx.z : 0;
    int khalf = SPLITK ? (K >> 1) : K;
    int kbeg = kz * khalf;

    const u16* pa0 = A + (size_t)min(m0 + w * 16 + srow, M - 1) * lda + skg;
    const u16* pa1 = A + (size_t)min(m0 + 64 + w * 16 + srow, M - 1) * lda + skg;
    const u16* pb0 = W + (size_t)min(n0 + w * 16 + srow, N - 1) * K + skg;
    const u16* pb1 = W + (size_t)min(n0 + 64 + w * 16 + srow, N - 1) * K + skg;
    u16* la0 = &As[(w * 16) * 32];
    u16* la1 = &As[(64 + w * 16) * 32];
    u16* lb0 = &Bs[(w * 16) * 32];
    u16* lb1 = &Bs[(64 + w * 16) * 32];

    f32x4 acc[4][4];
    #pragma unroll
    for (int i = 0; i < 4; i++)
        #pragma unroll
        for (int j = 0; j < 4; j++) acc[i][j] = (f32x4){0.f, 0.f, 0.f, 0.f};

    for (int kk = kbeg; kk < kbeg + khalf; kk += 32) {
        async_ld16(pa0 + kk, la0);
        async_ld16(pa1 + kk, la1);
        async_ld16(pb0 + kk, lb0);
        async_ld16(pb1 + kk, lb1);
        __syncthreads();
        bf16x8 af[4], bf[4];
        #pragma unroll
        for (int i = 0; i < 4; i++)
            af[i] = *reinterpret_cast<const bf16x8*>(&As[(wr*64 + i*16 + ll) * 32 + lg*8]);
        #pragma unroll
        for (int j = 0; j < 4; j++)
            bf[j] = *reinterpret_cast<const bf16x8*>(&Bs[(wc*64 + j*16 + ll) * 32 + lg*8]);
        #pragma unroll
        for (int i = 0; i < 4; i++)
            #pragma unroll
            for (int j = 0; j < 4; j++)
                acc[i][j] = __builtin_amdgcn_mfma_f32_16x16x32_bf16(af[i], bf[j], acc[i][j], 0, 0, 0);
        __syncthreads();
    }

    float bv[4];
    #pragma unroll
    for (int j = 0; j < 4; j++) {
        int n = n0 + wc*64 + j*16 + ll;
        bv[j] = (n < N && (!SPLITK || kz == 0)) ? bias[n] : 0.f;
    }
    #pragma unroll
    for (int i = 0; i < 4; i++) {
        if (VTOUT) {
            #pragma unroll
            for (int j = 0; j < 4; j++) {
                int n = n0 + wc*64 + j*16 + ll;
                int mb = m0 + wr*64 + i*16 + lg*4;
                if (n >= 1024) {
                    if (mb < T_TOK) {
                        ushort4 o;
                        o.x = f2bf(acc[i][j][0] + bv[j]);
                        o.y = f2bf(acc[i][j][1] + bv[j]);
                        o.z = f2bf(acc[i][j][2] + bv[j]);
                        o.w = f2bf(acc[i][j][3] + bv[j]);
                        *reinterpret_cast<ushort4*>(vtp + (size_t)(n - 1024) * VT_S + mb) = o;
                    }
                } else {
                    #pragma unroll
                    for (int r = 0; r < 4; r++) {
                        int mm = mb + r;
                        if (mm >= M) continue;
                        float v = acc[i][j][r] + bv[j];
                        if (n < 512) v *= QK_SCALE;
                        ((u16*)Cv)[(size_t)mm * QKS + n] = f2bf(v);
                    }
                }
            }
        } else {
            #pragma unroll
            for (int r = 0; r < 4; r++) {
                int m = m0 + wr*64 + i*16 + lg*4 + r;
                if (m >= M) continue;
                #pragma unroll
                for (int j = 0; j < 4; j++) {
                    int n = n0 + wc*64 + j*16 + ll;
                    if (n >= N) continue;
                    float v = acc[i][j][r] + bv[j];
                    if (RELU) v = fmaxf(v, 0.f);
                    v *= scale;
                    if (QSCALE && n < 512) v *= QK_SCALE;
                    if (HEADS) {
                        float* o = (float*)Cv;
                        if (n < 121)       o[(size_t)m * 121 + n] = v;
                        else if (n < 1452) (o + 435600)[(size_t)m * 1331 + (n - 121)] = v;
                        else               (o + 5227200)[(size_t)m * 10 + (n - 1452)] = v;
                    } else if (SPLITK && kz == 1) {
                        C1[(size_t)m * N + n] = v;
                    } else if (BF16OUT) {
                        ((u16*)Cv)[(size_t)m * N + n] = f2bf(v);
                    } else {
                        ((float*)Cv)[(size_t)m * N + n] = v;
                    }
                }
            }
        }
    }
}

// ---------------- MFMA flash attention: 32 q/wave, swapped QK^T ------------
// grid 3648 = 57 pairs x 8 z x 8 heads; h = bid&7 pins head->XCD.
// qkvb row stride QKS=1024 (Q|K only).
__global__ __launch_bounds__(64) void attn_mfma_kernel(
    const u16* __restrict__ qkvb, const u16* __restrict__ vt,
    u16* __restrict__ Op0, u16* __restrict__ Op1, float* __restrict__ mlpart)
{
    __shared__ u16 plds[2][16][66];
    int l = threadIdx.x;
    int lg = l >> 4, ll = l & 15;
    int bid = blockIdx.x;
    int h = bid & 7;
    int rest = bid >> 3;      // 0..455
    int z = rest / 57;        // 0..7
    int pr = rest - z * 57;   // 0..56

    #pragma unroll 1
    for (int tpart = 0; tpart < 2; tpart++) {
        if (tpart == 1 && pr == 56) break;
        int rank = (tpart == 0) ? pr : 112 - pr;
        int q0 = (112 - rank) * 32;

        bf16x8 qf0[2], qf1[2];
        int sql[2];
        bool qok[2];
        #pragma unroll
        for (int b = 0; b < 2; b++) {
            int qa = q0 + b * 16 + ll;
            qok[b] = qa < T_TOK;
            int qac = min(qa, T_TOK - 1);
            const u16* qrow = qkvb + (size_t)qac * QKS + h * HD + lg * 8;
            qf0[b] = *reinterpret_cast<const bf16x8*>(qrow);
            qf1[b] = *reinterpret_cast<const bf16x8*>(qrow + 32);
            sql[b] = step_of(qac);
        }
        int sl = max(sql[0], sql[1]), s2 = min(sql[0], sql[1]);
        #pragma unroll
        for (int off = 1; off < 16; off <<= 1) {
            sl = max(sl, __shfl_xor(sl, off));
            s2 = min(s2, __shfl_xor(s2, off));
        }
        int smax = sl, smin = s2;
        int limp[2], limb[2], limc[2];
        #pragma unroll
        for (int b = 0; b < 2; b++) {
            limp[b] = sql[b] * 10 + 9;
            limb[b] = 3000 + sql[b];
            limc[b] = 3300 + sql[b];
        }

        f32x4 oacc[2][4];
        #pragma unroll
        for (int b = 0; b < 2; b++)
            #pragma unroll
            for (int i = 0; i < 4; i++) oacc[b][i] = (f32x4){0.f, 0.f, 0.f, 0.f};
        float m[2] = {-INFINITY, -INFINITY};
        float ls[2] = {0.f, 0.f};

        #pragma unroll 1
        for (int kt = z; kt < NKT; kt += KSPLIT) {
            int kbase = kt * 64;
            int mn, mx;
            tile_minmax(kbase, mn, mx);
            if (mn > smax) continue;
            bool needmask = (mx > smin) || (kbase + 64 > T_TOK);

            bf16x8 kf0[4], kf1[4];
            #pragma unroll
            for (int f = 0; f < 4; f++) {
                int keyc = min(kbase + f * 16 + ll, T_TOK - 1);
                const u16* kr = qkvb + (size_t)keyc * QKS + 512 + h * HD + lg * 8;
                kf0[f] = *reinterpret_cast<const bf16x8*>(kr);
                kf1[f] = *reinterpret_cast<const bf16x8*>(kr + 32);
            }
            bf16x8 vf0[4], vf1[4];
            #pragma unroll
            for (int i = 0; i < 4; i++) {
                const u16* vr = vt + (size_t)(h * HD + i * 16 + ll) * VT_S + kbase + lg * 8;
                vf0[i] = *reinterpret_cast<const bf16x8*>(vr);
                vf1[i] = *reinterpret_cast<const bf16x8*>(vr + 32);
            }

            f32x4 sfr[2][4];
            __builtin_amdgcn_s_setprio(1);
            #pragma unroll
            for (int f = 0; f < 4; f++) {
                #pragma unroll
                for (int b = 0; b < 2; b++) {
                    f32x4 acc = (f32x4){0.f, 0.f, 0.f, 0.f};
                    acc = __builtin_amdgcn_mfma_f32_16x16x32_bf16(kf0[f], qf0[b], acc, 0, 0, 0);
                    acc = __builtin_amdgcn_mfma_f32_16x16x32_bf16(kf1[f], qf1[b], acc, 0, 0, 0);
                    sfr[b][f] = acc;
                }
            }
            __builtin_amdgcn_s_setprio(0);

            float rmax[2] = {-INFINITY, -INFINITY};
            if (!needmask) {
                #pragma unroll
                for (int f = 0; f < 4; f++)
                    #pragma unroll
                    for (int b = 0; b < 2; b++)
                        #pragma unroll
                        for (int r = 0; r < 4; r++) rmax[b] = fmaxf(rmax[b], sfr[b][f][r]);
            } else {
                #pragma unroll
                for (int f = 0; f < 4; f++)
                    #pragma unroll
                    for (int r = 0; r < 4; r++) {
                        int key = kbase + f * 16 + lg * 4 + r;
                        #pragma unroll
                        for (int b = 0; b < 2; b++) {
                            int lim = (key < 3000) ? limp[b] : ((key < 3300) ? limb[b] : limc[b]);
                            float v = sfr[b][f][r];
                            v = (key <= lim) ? v : -INFINITY;
                            sfr[b][f][r] = v;
                            rmax[b] = fmaxf(rmax[b], v);
                        }
                    }
            }
            if (!qok[0]) rmax[0] = -INFINITY;
            if (!qok[1]) rmax[1] = -INFINITY;
            #pragma unroll
            for (int b = 0; b < 2; b++) {
                rmax[b] = fmaxf(rmax[b], __shfl_xor(rmax[b], 16));
                rmax[b] = fmaxf(rmax[b], __shfl_xor(rmax[b], 32));
            }
            bool upd = (rmax[0] > m[0] + 8.f) || (rmax[1] > m[1] + 8.f);
            if (__any(upd)) {
                #pragma unroll
                for (int b = 0; b < 2; b++) {
                    float mn2 = fmaxf(m[b], rmax[b]);
                    float c = (m[b] == -INFINITY) ? 0.f : exp2f(m[b] - mn2);
                    m[b] = mn2;
                    ls[b] *= c;
                    f32x4 cv;
                    cv[0] = __shfl(c, lg * 4 + 0);
                    cv[1] = __shfl(c, lg * 4 + 1);
                    cv[2] = __shfl(c, lg * 4 + 2);
                    cv[3] = __shfl(c, lg * 4 + 3);
                    #pragma unroll
                    for (int i = 0; i < 4; i++) {
                        oacc[b][i][0] *= cv[0]; oacc[b][i][1] *= cv[1];
                        oacc[b][i][2] *= cv[2]; oacc[b][i][3] *= cv[3];
                    }
                }
            }
            if (!needmask) {
                #pragma unroll
                for (int b = 0; b < 2; b++)
                    #pragma unroll
                    for (int f = 0; f < 4; f++) {
                        float p0 = exp2f(sfr[b][f][0] - m[b]);
                        float p1 = exp2f(sfr[b][f][1] - m[b]);
                        float p2 = exp2f(sfr[b][f][2] - m[b]);
                        float p3 = exp2f(sfr[b][f][3] - m[b]);
                        ls[b] += (p0 + p1) + (p2 + p3);
                        *reinterpret_cast<u32*>(&plds[b][ll][f * 16 + lg * 4])     = cvt_pk_bf16(p0, p1);
                        *reinterpret_cast<u32*>(&plds[b][ll][f * 16 + lg * 4 + 2]) = cvt_pk_bf16(p2, p3);
                    }
            } else {
                #pragma unroll
                for (int b = 0; b < 2; b++)
                    #pragma unroll
                    for (int f = 0; f < 4; f++) {
                        float sv0 = sfr[b][f][0], sv1 = sfr[b][f][1];
                        float sv2 = sfr[b][f][2], sv3 = sfr[b][f][3];
                        float p0 = (sv0 == -INFINITY) ? 0.f : exp2f(sv0 - m[b]);
                        float p1 = (sv1 == -INFINITY) ? 0.f : exp2f(sv1 - m[b]);
                        float p2 = (sv2 == -INFINITY) ? 0.f : exp2f(sv2 - m[b]);
                        float p3 = (sv3 == -INFINITY) ? 0.f : exp2f(sv3 - m[b]);
                        ls[b] += (p0 + p1) + (p2 + p3);
                        *reinterpret_cast<u32*>(&plds[b][ll][f * 16 + lg * 4])     = cvt_pk_bf16(p0, p1);
                        *reinterpret_cast<u32*>(&plds[b][ll][f * 16 + lg * 4 + 2]) = cvt_pk_bf16(p2, p3);
                    }
            }
            __builtin_amdgcn_s_setprio(1);
            #pragma unroll
            for (int b = 0; b < 2; b++) {
                bf16x8 pf0 = *reinterpret_cast<const bf16x8*>(&plds[b][ll][lg * 8]);
                #pragma unroll
                for (int i = 0; i < 4; i++)
                    oacc[b][i] = __builtin_amdgcn_mfma_f32_16x16x32_bf16(pf0, vf0[i], oacc[b][i], 0, 0, 0);
                bf16x8 pf1 = *reinterpret_cast<const bf16x8*>(&plds[b][ll][32 + lg * 8]);
                #pragma unroll
                for (int i = 0; i < 4; i++)
                    oacc[b][i] = __builtin_amdgcn_mfma_f32_16x16x32_bf16(pf1, vf1[i], oacc[b][i], 0, 0, 0);
            }
            __builtin_amdgcn_s_setprio(0);
        }

        #pragma unroll
        for (int b = 0; b < 2; b++) {
            ls[b] += __shfl_xor(ls[b], 16);
            ls[b] += __shfl_xor(ls[b], 32);
        }
        u16* Ob = (z < 5) ? (Op0 + (size_t)z * ZSLICE) : (Op1 + (size_t)(z - 5) * ZSLICE);
        #pragma unroll
        for (int b = 0; b < 2; b++)
            #pragma unroll
            for (int r = 0; r < 4; r++) {
                int q = q0 + b * 16 + lg * 4 + r;
                if (q >= T_TOK) continue;
                size_t ob = ((size_t)h * 3600 + q) * 64;
                #pragma unroll
                for (int i = 0; i < 4; i++)
                    Ob[ob + i * 16 + ll] = f2bf(oacc[b][i][r]);
            }
        if (lg == 0) {
            #pragma unroll
            for (int b = 0; b < 2; b++) {
                int qa = q0 + b * 16 + ll;
                if (qa < T_TOK) {
                    size_t mi = ((size_t)(z * 8 + h) * 3600 + qa) * 2;
                    mlpart[mi]     = m[b];
                    mlpart[mi + 1] = ls[b];
                }
            }
        }
    }
}

// ---------------- merge KSPLIT partials -> obb (vectorized) ----------------
__global__ __launch_bounds__(256) void attn_merge_kernel(
    const u16* __restrict__ Op0, const u16* __restrict__ Op1,
    const float* __restrict__ mlpart, u16* __restrict__ obb)
{
    int t = threadIdx.x;
    int h = blockIdx.y;
    int q = blockIdx.x * 64 + (t >> 2);
    if (q >= T_TOK) return;
    int dg = (t & 3) * 16;
    float mz[KSPLIT], lz[KSPLIT];
    #pragma unroll
    for (int zz = 0; zz < KSPLIT; zz++) {
        size_t mi = ((size_t)(zz * 8 + h) * 3600 + q) * 2;
        mz[zz] = mlpart[mi];
        lz[zz] = mlpart[mi + 1];
    }
    float M = -INFINITY;
    #pragma unroll
    for (int zz = 0; zz < KSPLIT; zz++) if (lz[zz] > 0.f) M = fmaxf(M, mz[zz]);
    float wz[KSPLIT], den = 0.f;
    #pragma unroll
    for (int zz = 0; zz < KSPLIT; zz++) {
        wz[zz] = (lz[zz] > 0.f) ? exp2f(mz[zz] - M) : 0.f;
        den += wz[zz] * lz[zz];
    }
    float inv = (den > 0.f) ? 1.f / den : 0.f;
    size_t qoff = ((size_t)h * 3600 + q) * 64 + dg;
    float acc[16];
    #pragma unroll
    for (int e = 0; e < 16; e++) acc[e] = 0.f;
    #pragma unroll
    for (int zz = 0; zz < KSPLIT; zz++) {
        const u16* Ob = (zz < 5) ? (Op0 + (size_t)zz * ZSLICE) : (Op1 + (size_t)(zz - 5) * ZSLICE);
        bf16x8 v0 = *reinterpret_cast<const bf16x8*>(Ob + qoff);
        bf16x8 v1 = *reinterpret_cast<const bf16x8*>(Ob + qoff + 8);
        float w = wz[zz];
        #pragma unroll
        for (int e = 0; e < 8; e++) {
            acc[e]     += bf2f((u16)v0[e]) * w;
            acc[8 + e] += bf2f((u16)v1[e]) * w;
        }
    }
    u16 o16[16];
    #pragma unroll
    for (int e = 0; e < 16; e++) o16[e] = f2bf(acc[e] * inv);
    u16* op = obb + (size_t)q * D_ + h * HD + dg;
    *reinterpret_cast<bf16x8*>(op)     = *reinterpret_cast<const bf16x8*>(&o16[0]);
    *reinterpret_cast<bf16x8*>(op + 8) = *reinterpret_cast<const bf16x8*>(&o16[8]);
}

// ---------------- residual add (two partials) + LayerNorm (float4) --------
__global__ __launch_bounds__(128) void add_ln3_kernel(
    float* __restrict__ x, const float* __restrict__ r1, const float* __restrict__ r2,
    const float* __restrict__ g, const float* __restrict__ b,
    u16* __restrict__ xb)
{
    int row = blockIdx.x, t = threadIdx.x;   // 128 threads, 4 elems each
    size_t base = (size_t)row * D_ + t * 4;
    float4 xv = *reinterpret_cast<const float4*>(&x[base]);
    float4 a1 = *reinterpret_cast<const float4*>(&r1[base]);
    float4 a2 = *reinterpret_cast<const float4*>(&r2[base]);
    float v0 = xv.x + a1.x + a2.x;
    float v1 = xv.y + a1.y + a2.y;
    float v2 = xv.z + a1.z + a2.z;
    float v3 = xv.w + a1.w + a2.w;
    float s = (v0 + v1) + (v2 + v3);
    float ss = (v0 * v0 + v1 * v1) + (v2 * v2 + v3 * v3);
    #pragma unroll
    for (int off = 32; off > 0; off >>= 1) {
        s  += __shfl_xor(s, off);
        ss += __shfl_xor(ss, off);
    }
    __shared__ float rs[2], rss[2];
    int w = t >> 6;
    if ((t & 63) == 0) { rs[w] = s; rss[w] = ss; }
    __syncthreads();
    s  = rs[0] + rs[1];
    ss = rss[0] + rss[1];
    float mean = s * (1.f / 512.f);
    float var = ss * (1.f / 512.f) - mean * mean;
    float rstd = rsqrtf(var + 1e-5f);
    float4 gv = *reinterpret_cast<const float4*>(&g[t * 4]);
    float4 bv = *reinterpret_cast<const float4*>(&b[t * 4]);
    float o0 = (v0 - mean) * rstd * gv.x + bv.x;
    float o1 = (v1 - mean) * rstd * gv.y + bv.y;
    float o2 = (v2 - mean) * rstd * gv.z + bv.z;
    float o3 = (v3 - mean) * rstd * gv.w + bv.w;
    *reinterpret_cast<float4*>(&x[base]) = make_float4(o0, o1, o2, o3);
    ushort4 ob;
    ob.x = f2bf(o0); ob.y = f2bf(o1); ob.z = f2bf(o2); ob.w = f2bf(o3);
    *reinterpret_cast<ushort4*>(&xb[base]) = ob;
}

// ---------------------------------------------------------------------------
extern "C" void kernel_launch(void* const* d_in, const int* in_sizes, int n_in,
                              void* d_out, int out_size, void* d_ws, size_t ws_size,
                              hipStream_t stream)
{
    const float* player_xs = (const float*)d_in[0];
    const float* player_ys = (const float*)d_in[1];
    const float* player_hs = (const float*)d_in[2];
    const float* ball_xs   = (const float*)d_in[3];
    const float* ball_ys   = (const float*)d_in[4];
    const float* ball_zs   = (const float*)d_in[5];
    const float* emb_table = (const float*)d_in[6];
    const float* ball_emb  = (const float*)d_in[7];
    const float* cls_emb   = (const float*)d_in[8];
    const float* pW0 = (const float*)d_in[9];   const float* pb0 = (const float*)d_in[10];
    const float* pW1 = (const float*)d_in[11];  const float* pb1 = (const float*)d_in[12];
    const float* pW2 = (const float*)d_in[13];  const float* pb2 = (const float*)d_in[14];
    const float* bW0 = (const float*)d_in[15];  const float* bb0 = (const float*)d_in[16];
    const float* bW1 = (const float*)d_in[17];  const float* bb1 = (const float*)d_in[18];
    const float* bW2 = (const float*)d_in[19];  const float* bb2 = (const float*)d_in[20];
    const float* Wqkv = (const float*)d_in[21]; const float* bqkv = (const float*)d_in[22];
    const float* Wo  = (const float*)d_in[23];  const float* bo  = (const float*)d_in[24];
    const float* W1f = (const float*)d_in[25];  const float* b1f = (const float*)d_in[26];
    const float* W2f = (const float*)d_in[27];  const float* b2f = (const float*)d_in[28];
    const float* g1  = (const float*)d_in[29];  const float* be1 = (const float*)d_in[30];
    const float* g2  = (const float*)d_in[31];  const float* be2 = (const float*)d_in[32];
    const float* cpW = (const float*)d_in[33];  const float* cpb = (const float*)d_in[34];
    const float* cbW = (const float*)d_in[35];  const float* cbb = (const float*)d_in[36];
    const float* csW = (const float*)d_in[37];  const float* csb = (const float*)d_in[38];
    const int* pidx = (const int*)d_in[39];

    // workspace (51.6 MB): x | big | obr | tmp2
    float* x    = (float*)d_ws;            // 1,843,200 f32
    float* big  = x + 1843200;             // 7,372,800 f32
    float* obr  = big + 7372800;           // 1,843,200 f32
    float* tmp2 = obr + 1843200;           // 1,843,200 f32
    u16*   qkvb   = (u16*)big;             // [3600][1024] bf16 (Q|K, compact)
    u16*   Op0    = (u16*)(big + 2764800); // z-slices 0-4
    u16*   wbh    = (u16*)(big + 6681600); // head weights bf16
    float* bhead  = big + 7100000;         // packed head bias
    u16*   ff1b   = (u16*)big;             // [3600][2048] bf16 (FF phase)
    float* r2buf  = big + 4000000;         // split-K second partial
    u16*   obb    = (u16*)obr;             // [3600][512] bf16
    u16*   xb     = (u16*)(obr + 921600);  // [3600][512] bf16
    u16*   vt     = (u16*)tmp2;            // [512][3648] bf16
    float* mlpart = tmp2 + 1000000;        // [8][8][3600][2] f32
    float* out = (float*)d_out;
    u16* wpack  = (u16*)d_out;
    u16* wqkv_b = wpack;                   // 1536*512
    u16* wo_b   = wpack + 786432;          // 512*512
    u16* w1f_b  = wpack + 1048576;         // 2048*512
    u16* w2f_b  = wpack + 2097152;         // 512*2048
    u16* Op1    = wpack + 3145728;         // z-slices 5-7
    float* IN = big;                       // 3600*24
    float* h0 = big + 131072;              // 3600*128
    float* h1 = big + 131072 + 460800;     // 3600*256

    gather_kernel<<<15, 256, 0, stream>>>(
        player_xs, player_ys, player_hs, ball_xs, ball_ys, ball_zs,
        emb_table, ball_emb, cls_emb, pidx, IN, x, xb);

    gemm_tok<1,0><<<dim3(24, 1, 2), 256, 0, stream>>>(
        IN, pW0, pb0, h0, IN + 3000*24, bW0, bb0, h0 + 3000*128, nullptr,
        3000, 300, 128, 23, 24, 1.f);
    gemm_tok<1,0><<<dim3(24, 2, 2), 256, 0, stream>>>(
        h0, pW1, pb1, h1, h0 + 3000*128, bW1, bb1, h1 + 3000*256, nullptr,
        3000, 300, 256, 128, 128, 1.f);
    gemm_tok<0,1><<<dim3(24, 4, 2), 256, 0, stream>>>(
        h1, pW2, pb2, x, h1 + 3000*256, bW2, bb2, x + 3000*512, xb,
        3000, 300, 512, 256, 256, SQRT512);

    for (int l = 0; l < 4; l++) {
        const float* Wqkv_l = Wqkv + (size_t)l * 1536 * 512;
        const float* bqkv_l = bqkv + (size_t)l * 1536;
        const float* bo_l   = bo   + (size_t)l * 512;
        const float* Wo_l   = Wo   + (size_t)l * 512 * 512;
        const float* W1f_l  = W1f  + (size_t)l * 2048 * 512;
        const float* b1f_l  = b1f  + (size_t)l * 2048;
        const float* W2f_l  = W2f  + (size_t)l * 512 * 2048;
        const float* b2f_l  = b2f  + (size_t)l * 512;

        w2b4_kernel<<<1024, 256, 0, stream>>>(Wqkv_l, Wo_l, W1f_l, W2f_l, wpack, vt);
        gemm_async<0,1,1,0,0,1><<<dim3(29, 12), 256, 0, stream>>>(xb, wqkv_b, bqkv_l, qkvb, nullptr, vt, 3600, 1536, 512, 512, 1.f);
        attn_mfma_kernel<<<57 * 8 * 8, 64, 0, stream>>>(qkvb, vt, Op0, Op1, mlpart);
        attn_merge_kernel<<<dim3(57, 8), 256, 0, stream>>>(Op0, Op1, mlpart, obb);
        gemm_async<0,0,0,1,0,0><<<dim3(29, 4, 2), 256, 0, stream>>>(obb, wo_b, bo_l, tmp2, r2buf, nullptr, 3600, 512, 512, 512, 1.f);
        add_ln3_kernel<<<3600, 128, 0, stream>>>(x, tmp2, r2buf, g1 + (size_t)l * 512, be1 + (size_t)l * 512, xb);
        gemm_async<1,1,0,0,0,0><<<dim3(29, 16), 256, 0, stream>>>(xb, w1f_b, b1f_l, ff1b, nullptr, nullptr, 3600, 2048, 512, 512, 1.f);
        gemm_async<0,0,0,1,0,0><<<dim3(29, 4, 2), 256, 0, stream>>>(ff1b, w2f_b, b2f_l, tmp2, r2buf, nullptr, 3600, 512, 2048, 2048, 1.f);
        add_ln3_kernel<<<3600, 128, 0, stream>>>(x, tmp2, r2buf, g2 + (size_t)l * 512, be2 + (size_t)l * 512, xb);
    }

    w2bh_kernel<<<732, 256, 0, stream>>>(cpW, cbW, csW, cpb, cbb, csb, wbh, bhead);
    gemm_async<0,0,0,0,1,0><<<dim3(29, 12), 256, 0, stream>>>(xb, wbh, bhead, out, nullptr, nullptr, 3600, 1462, 512, 512, 1.f);
}

// Round 21
// 871.652 us; speedup vs baseline: 1.1033x; 1.0247x over previous
//
#include <hip/hip_runtime.h>
#include <hip/hip_bf16.h>

typedef unsigned short u16;
typedef unsigned int u32;
typedef __attribute__((ext_vector_type(8))) short bf16x8;
typedef __attribute__((ext_vector_type(4))) float f32x4;

#define T_TOK 3600
#define D_    512
#define H_    8
#define HD    64
#define NKT   57
#define VT_S  3648
#define KSPLIT 8
#define ZSLICE 1843200  // u16 per z-slice: 8*3600*64
#define QKS   1024      // qkvb row stride (Q|K only)
#define SQRT512 22.627416997969522f
#define QK_SCALE 0.18033688011112042f // 0.125 * log2(e)

__device__ __forceinline__ u16 f2bf(float f) {
    unsigned int x = __float_as_uint(f);
    unsigned int lsb = (x >> 16) & 1;
    return (u16)((x + 0x7fffu + lsb) >> 16);
}
__device__ __forceinline__ float bf2f(u16 u) {
    return __uint_as_float(((unsigned int)u) << 16);
}
__device__ __forceinline__ u32 cvt_pk_bf16(float a, float b) {
    u32 r;
    asm("v_cvt_pk_bf16_f32 %0, %1, %2" : "=v"(r) : "v"(a), "v"(b));
    return r;
}
__device__ __forceinline__ void async_ld16(const void* g, void* l) {
    __builtin_amdgcn_global_load_lds(
        (const __attribute__((address_space(1))) void*)g,
        (__attribute__((address_space(3))) void*)l, 16, 0, 0);
}
__device__ __forceinline__ int step_of(int i) {
    return (i < 3000) ? (i / 10) : ((i < 3300) ? (i - 3000) : (i - 3300));
}
__device__ __forceinline__ void tile_minmax(int kbase, int& mn, int& mx) {
    int a = kbase, b = min(kbase + 63, T_TOK - 1);
    mn = 0x7fffffff; mx = -1;
    if (a < 3000)              { mn = min(mn, a / 10);              mx = max(mx, min(b, 2999) / 10); }
    if (b >= 3000 && a < 3300) { mn = min(mn, max(a, 3000) - 3000); mx = max(mx, min(b, 3299) - 3000); }
    if (b >= 3300)             { mn = min(mn, max(a, 3300) - 3300); mx = max(mx, b - 3300); }
}

// ---------------- gather: IN[3600][24] + cls rows of x and xb --------------
__global__ __launch_bounds__(256) void gather_kernel(
    const float* __restrict__ pxs, const float* __restrict__ pys, const float* __restrict__ phs,
    const float* __restrict__ bxs, const float* __restrict__ bys, const float* __restrict__ bzs,
    const float* __restrict__ emb_table, const float* __restrict__ ball_emb,
    const float* __restrict__ cls_emb, const int* __restrict__ pidx,
    float* __restrict__ IN, float* __restrict__ x, u16* __restrict__ xb)
{
    int g = blockIdx.x * 256 + threadIdx.x;
    if (g < 3300) {
        float* row = IN + g * 24;
        if (g < 3000) {
            int id = pidx[g];
            #pragma unroll
            for (int e = 0; e < 20; e++) row[e] = emb_table[id * 20 + e];
            row[20] = pxs[g]; row[21] = pys[g]; row[22] = phs[g];
        } else {
            int b = g - 3000;
            #pragma unroll
            for (int e = 0; e < 20; e++) row[e] = ball_emb[e];
            row[20] = bxs[b]; row[21] = bys[b]; row[22] = bzs[b];
        }
        row[23] = 0.f;
    }
    for (int i = g; i < 300 * 512; i += 3840) {
        float v = cls_emb[i & 511];
        x[3300 * 512 + i] = v;
        xb[3300 * 512 + i] = f2bf(v);
    }
}

// ---------------- per-layer weight convert + vt-pad zero -------------------
__global__ __launch_bounds__(256) void w2b4_kernel(
    const float* __restrict__ s0, const float* __restrict__ s1,
    const float* __restrict__ s2, const float* __restrict__ s3,
    u16* __restrict__ dst, u16* __restrict__ vt)
{
    int stride = gridDim.x * 256;
    for (int i = blockIdx.x * 256 + threadIdx.x; i < 786432; i += stride) {
        const float4* src;
        int j = i;
        if (j < 196608)      { src = (const float4*)s0; }
        else if (j < 262144) { src = (const float4*)s1; j -= 196608; }
        else if (j < 524288) { src = (const float4*)s2; j -= 262144; }
        else                 { src = (const float4*)s3; j -= 524288; }
        float4 v = src[j];
        ushort4 o;
        o.x = f2bf(v.x); o.y = f2bf(v.y); o.z = f2bf(v.z); o.w = f2bf(v.w);
        reinterpret_cast<ushort4*>(dst)[i] = o;
    }
    // zero vt's pad tokens [3600,3648) on all 512 rows
    for (int i = blockIdx.x * 256 + threadIdx.x; i < 512 * 64; i += stride) {
        int row = i >> 6, c = i & 63;
        if (c < 48) vt[(size_t)row * VT_S + 3600 + c] = 0;
    }
}

// ---------------- head-weight + bias pack ----------------------------------
__global__ __launch_bounds__(256) void w2bh_kernel(
    const float* __restrict__ cp, const float* __restrict__ cb,
    const float* __restrict__ cs, const float* __restrict__ bp,
    const float* __restrict__ bb, const float* __restrict__ bs,
    u16* __restrict__ dst, float* __restrict__ bias)
{
    int stride = gridDim.x * 256;
    for (int i = blockIdx.x * 256 + threadIdx.x; i < 187136; i += stride) {
        const float4* src;
        int j = i;
        if (j < 15488)       { src = (const float4*)cp; }
        else if (j < 185856) { src = (const float4*)cb; j -= 15488; }
        else                 { src = (const float4*)cs; j -= 185856; }
        float4 v = src[j];
        ushort4 o;
        o.x = f2bf(v.x); o.y = f2bf(v.y); o.z = f2bf(v.z); o.w = f2bf(v.w);
        reinterpret_cast<ushort4*>(dst)[i] = o;
    }
    int g = blockIdx.x * 256 + threadIdx.x;
    if (g < 1462)
        bias[g] = (g < 121) ? bp[g] : (g < 1452) ? bb[g - 121] : bs[g - 1452];
}

// ---------------- fp32-input token GEMM: player(z=0) / ball(z=1) ----------
__device__ __forceinline__ void stage_f32(
    const float* __restrict__ src, int nrows, int K, int lda,
    int r0, int kk, int srow, int scg, u16* dst)
{
    u16 tmp[16];
    int rr = r0 + srow;
    if (rr < nrows) {
        if (((lda & 3) == 0) && (kk + scg + 16 <= K)) {
            const float4* p = reinterpret_cast<const float4*>(src + (size_t)rr * lda + kk + scg);
            #pragma unroll
            for (int q = 0; q < 4; q++) {
                float4 v = p[q];
                tmp[q*4+0] = f2bf(v.x); tmp[q*4+1] = f2bf(v.y);
                tmp[q*4+2] = f2bf(v.z); tmp[q*4+3] = f2bf(v.w);
            }
        } else {
            #pragma unroll
            for (int e = 0; e < 16; e++) {
                int kc = kk + scg + e;
                tmp[e] = (kc < K) ? f2bf(src[(size_t)rr * lda + kc]) : (u16)0;
            }
        }
    } else {
        #pragma unroll
        for (int e = 0; e < 16; e++) tmp[e] = 0;
    }
    *reinterpret_cast<bf16x8*>(dst)     = *reinterpret_cast<const bf16x8*>(&tmp[0]);
    *reinterpret_cast<bf16x8*>(dst + 8) = *reinterpret_cast<const bf16x8*>(&tmp[8]);
}

template<int RELU, int DUAL>
__global__ __launch_bounds__(256) void gemm_tok(
    const float* __restrict__ A0, const float* __restrict__ W0p,
    const float* __restrict__ b0p, float* __restrict__ C0,
    const float* __restrict__ A1, const float* __restrict__ W1p,
    const float* __restrict__ b1p, float* __restrict__ C1,
    u16* __restrict__ Cb,
    int M0, int M1, int N, int K, int lda, float scale)
{
    int zz = blockIdx.z;
    int M = zz ? M1 : M0;
    int m0 = blockIdx.x * 128;
    if (m0 >= M) return;
    const float* A = zz ? A1 : A0;
    const float* W = zz ? W1p : W0p;
    const float* bias = zz ? b1p : b0p;
    float* C = zz ? C1 : C0;
    u16* CbL = DUAL ? (zz ? Cb + (size_t)M0 * N : Cb) : nullptr;

    __shared__ u16 As[128][40];
    __shared__ u16 Bs[128][40];
    int t = threadIdx.x;
    int w = t >> 6, l = t & 63;
    int ll = l & 15, lg = l >> 4;
    int wr = w >> 1, wc = w & 1;
    int n0 = blockIdx.y * 128;
    int srow = t >> 1;
    int scg  = (t & 1) * 16;

    f32x4 acc[4][4];
    #pragma unroll
    for (int i = 0; i < 4; i++)
        #pragma unroll
        for (int j = 0; j < 4; j++) acc[i][j] = (f32x4){0.f, 0.f, 0.f, 0.f};

    for (int kk = 0; kk < K; kk += 32) {
        stage_f32(A, M, K, lda, m0, kk, srow, scg, &As[srow][scg]);
        stage_f32(W, N, K, K, n0, kk, srow, scg, &Bs[srow][scg]);
        __syncthreads();
        bf16x8 af[4], bf[4];
        #pragma unroll
        for (int i = 0; i < 4; i++)
            af[i] = *reinterpret_cast<const bf16x8*>(&As[wr*64 + i*16 + ll][lg*8]);
        #pragma unroll
        for (int j = 0; j < 4; j++)
            bf[j] = *reinterpret_cast<const bf16x8*>(&Bs[wc*64 + j*16 + ll][lg*8]);
        #pragma unroll
        for (int i = 0; i < 4; i++)
            #pragma unroll
            for (int j = 0; j < 4; j++)
                acc[i][j] = __builtin_amdgcn_mfma_f32_16x16x32_bf16(af[i], bf[j], acc[i][j], 0, 0, 0);
        __syncthreads();
    }

    float bv[4];
    #pragma unroll
    for (int j = 0; j < 4; j++) {
        int n = n0 + wc*64 + j*16 + ll;
        bv[j] = (n < N) ? bias[n] : 0.f;
    }
    #pragma unroll
    for (int i = 0; i < 4; i++) {
        #pragma unroll
        for (int r = 0; r < 4; r++) {
            int m = m0 + wr*64 + i*16 + lg*4 + r;
            if (m >= M) continue;
            #pragma unroll
            for (int j = 0; j < 4; j++) {
                int n = n0 + wc*64 + j*16 + ll;
                if (n >= N) continue;
                float v = acc[i][j][r] + bv[j];
                if (RELU) v = fmaxf(v, 0.f);
                v *= scale;
                C[(size_t)m * N + n] = v;
                if (DUAL) CbL[(size_t)m * N + n] = f2bf(v);
            }
        }
    }
}

// ---------------- bf16 MFMA GEMM, 2-phase pipelined global_load_lds --------
// Double-buffered LDS; tile t+1's loads issued before computing tile t;
// ONE __syncthreads per K-step (drains prefetch vmcnt + guards buffer reuse).
template<int RELU, int BF16OUT, int QSCALE, int SPLITK, int HEADS, int VTOUT>
__global__ __launch_bounds__(256) void gemm_async(
    const u16* __restrict__ A, const u16* __restrict__ W,
    const float* __restrict__ bias, void* __restrict__ Cv, float* __restrict__ C1,
    u16* __restrict__ vtp, int M, int N, int K, int lda, float scale)
{
    __shared__ u16 As[2][4096];   // [buf][128][32]
    __shared__ u16 Bs[2][4096];
    int t = threadIdx.x;
    int w = t >> 6, l = t & 63;
    int ll = l & 15, lg = l >> 4;
    int wr = w >> 1, wc = w & 1;
    int m0 = blockIdx.x * 128, n0 = blockIdx.y * 128;
    int srow = l >> 2;
    int skg  = (l & 3) * 8;
    int kz = SPLITK ? blockIdx.z : 0;
    int khalf = SPLITK ? (K >> 1) : K;
    int kbeg = kz * khalf;
    int nt = khalf >> 5;   // K-steps of 32

    const u16* pa0 = A + (size_t)min(m0 + w * 16 + srow, M - 1) * lda + skg;
    const u16* pa1 = A + (size_t)min(m0 + 64 + w * 16 + srow, M - 1) * lda + skg;
    const u16* pb0 = W + (size_t)min(n0 + w * 16 + srow, N - 1) * K + skg;
    const u16* pb1 = W + (size_t)min(n0 + 64 + w * 16 + srow, N - 1) * K + skg;
    int la0 = (w * 16) * 32;
    int la1 = (64 + w * 16) * 32;

    f32x4 acc[4][4];
    #pragma unroll
    for (int i = 0; i < 4; i++)
        #pragma unroll
        for (int j = 0; j < 4; j++) acc[i][j] = (f32x4){0.f, 0.f, 0.f, 0.f};

    // prologue: stage tile 0 into buf 0
    async_ld16(pa0 + kbeg, &As[0][la0]);
    async_ld16(pa1 + kbeg, &As[0][la1]);
    async_ld16(pb0 + kbeg, &Bs[0][la0]);
    async_ld16(pb1 + kbeg, &Bs[0][la1]);
    __syncthreads();

    int cur = 0;
    for (int it = 0; it < nt; ++it) {
        int kk = kbeg + (it << 5);
        if (it + 1 < nt) {   // prefetch next tile into buf^1 (hidden under MFMA)
            int kn = kk + 32;
            async_ld16(pa0 + kn, &As[cur ^ 1][la0]);
            async_ld16(pa1 + kn, &As[cur ^ 1][la1]);
            async_ld16(pb0 + kn, &Bs[cur ^ 1][la0]);
            async_ld16(pb1 + kn, &Bs[cur ^ 1][la1]);
        }
        bf16x8 af[4], bf[4];
        #pragma unroll
        for (int i = 0; i < 4; i++)
            af[i] = *reinterpret_cast<const bf16x8*>(&As[cur][(wr*64 + i*16 + ll) * 32 + lg*8]);
        #pragma unroll
        for (int j = 0; j < 4; j++)
            bf[j] = *reinterpret_cast<const bf16x8*>(&Bs[cur][(wc*64 + j*16 + ll) * 32 + lg*8]);
        #pragma unroll
        for (int i = 0; i < 4; i++)
            #pragma unroll
            for (int j = 0; j < 4; j++)
                acc[i][j] = __builtin_amdgcn_mfma_f32_16x16x32_bf16(af[i], bf[j], acc[i][j], 0, 0, 0);
        __syncthreads();   // drains prefetch vmcnt; all reads of buf[cur] done
        cur ^= 1;
    }

    float bv[4];
    #pragma unroll
    for (int j = 0; j < 4; j++) {
        int n = n0 + wc*64 + j*16 + ll;
        bv[j] = (n < N && (!SPLITK || kz == 0)) ? bias[n] : 0.f;
    }
    #pragma unroll
    for (int i = 0; i < 4; i++) {
        if (VTOUT) {
            #pragma unroll
            for (int j = 0; j < 4; j++) {
                int n = n0 + wc*64 + j*16 + ll;
                int mb = m0 + wr*64 + i*16 + lg*4;
                if (n >= 1024) {
                    if (mb < T_TOK) {
                        ushort4 o;
                        o.x = f2bf(acc[i][j][0] + bv[j]);
                        o.y = f2bf(acc[i][j][1] + bv[j]);
                        o.z = f2bf(acc[i][j][2] + bv[j]);
                        o.w = f2bf(acc[i][j][3] + bv[j]);
                        *reinterpret_cast<ushort4*>(vtp + (size_t)(n - 1024) * VT_S + mb) = o;
                    }
                } else {
                    #pragma unroll
                    for (int r = 0; r < 4; r++) {
                        int mm = mb + r;
                        if (mm >= M) continue;
                        float v = acc[i][j][r] + bv[j];
                        if (n < 512) v *= QK_SCALE;
                        ((u16*)Cv)[(size_t)mm * QKS + n] = f2bf(v);
                    }
                }
            }
        } else {
            #pragma unroll
            for (int r = 0; r < 4; r++) {
                int m = m0 + wr*64 + i*16 + lg*4 + r;
                if (m >= M) continue;
                #pragma unroll
                for (int j = 0; j < 4; j++) {
                    int n = n0 + wc*64 + j*16 + ll;
                    if (n >= N) continue;
                    float v = acc[i][j][r] + bv[j];
                    if (RELU) v = fmaxf(v, 0.f);
                    v *= scale;
                    if (QSCALE && n < 512) v *= QK_SCALE;
                    if (HEADS) {
                        float* o = (float*)Cv;
                        if (n < 121)       o[(size_t)m * 121 + n] = v;
                        else if (n < 1452) (o + 435600)[(size_t)m * 1331 + (n - 121)] = v;
                        else               (o + 5227200)[(size_t)m * 10 + (n - 1452)] = v;
                    } else if (SPLITK && kz == 1) {
                        C1[(size_t)m * N + n] = v;
                    } else if (BF16OUT) {
                        ((u16*)Cv)[(size_t)m * N + n] = f2bf(v);
                    } else {
                        ((float*)Cv)[(size_t)m * N + n] = v;
                    }
                }
            }
        }
    }
}

// ---------------- MFMA flash attention: 32 q/wave, swapped QK^T ------------
// grid 3648 = 57 pairs x 8 z x 8 heads; h = bid&7 pins head->XCD.
// qkvb row stride QKS=1024 (Q|K only).
__global__ __launch_bounds__(64) void attn_mfma_kernel(
    const u16* __restrict__ qkvb, const u16* __restrict__ vt,
    u16* __restrict__ Op0, u16* __restrict__ Op1, float* __restrict__ mlpart)
{
    __shared__ u16 plds[2][16][66];
    int l = threadIdx.x;
    int lg = l >> 4, ll = l & 15;
    int bid = blockIdx.x;
    int h = bid & 7;
    int rest = bid >> 3;      // 0..455
    int z = rest / 57;        // 0..7
    int pr = rest - z * 57;   // 0..56

    #pragma unroll 1
    for (int tpart = 0; tpart < 2; tpart++) {
        if (tpart == 1 && pr == 56) break;
        int rank = (tpart == 0) ? pr : 112 - pr;
        int q0 = (112 - rank) * 32;

        bf16x8 qf0[2], qf1[2];
        int sql[2];
        bool qok[2];
        #pragma unroll
        for (int b = 0; b < 2; b++) {
            int qa = q0 + b * 16 + ll;
            qok[b] = qa < T_TOK;
            int qac = min(qa, T_TOK - 1);
            const u16* qrow = qkvb + (size_t)qac * QKS + h * HD + lg * 8;
            qf0[b] = *reinterpret_cast<const bf16x8*>(qrow);
            qf1[b] = *reinterpret_cast<const bf16x8*>(qrow + 32);
            sql[b] = step_of(qac);
        }
        int sl = max(sql[0], sql[1]), s2 = min(sql[0], sql[1]);
        #pragma unroll
        for (int off = 1; off < 16; off <<= 1) {
            sl = max(sl, __shfl_xor(sl, off));
            s2 = min(s2, __shfl_xor(s2, off));
        }
        int smax = sl, smin = s2;
        int limp[2], limb[2], limc[2];
        #pragma unroll
        for (int b = 0; b < 2; b++) {
            limp[b] = sql[b] * 10 + 9;
            limb[b] = 3000 + sql[b];
            limc[b] = 3300 + sql[b];
        }

        f32x4 oacc[2][4];
        #pragma unroll
        for (int b = 0; b < 2; b++)
            #pragma unroll
            for (int i = 0; i < 4; i++) oacc[b][i] = (f32x4){0.f, 0.f, 0.f, 0.f};
        float m[2] = {-INFINITY, -INFINITY};
        float ls[2] = {0.f, 0.f};

        #pragma unroll 1
        for (int kt = z; kt < NKT; kt += KSPLIT) {
            int kbase = kt * 64;
            int mn, mx;
            tile_minmax(kbase, mn, mx);
            if (mn > smax) continue;
            bool needmask = (mx > smin) || (kbase + 64 > T_TOK);

            bf16x8 kf0[4], kf1[4];
            #pragma unroll
            for (int f = 0; f < 4; f++) {
                int keyc = min(kbase + f * 16 + ll, T_TOK - 1);
                const u16* kr = qkvb + (size_t)keyc * QKS + 512 + h * HD + lg * 8;
                kf0[f] = *reinterpret_cast<const bf16x8*>(kr);
                kf1[f] = *reinterpret_cast<const bf16x8*>(kr + 32);
            }
            bf16x8 vf0[4], vf1[4];
            #pragma unroll
            for (int i = 0; i < 4; i++) {
                const u16* vr = vt + (size_t)(h * HD + i * 16 + ll) * VT_S + kbase + lg * 8;
                vf0[i] = *reinterpret_cast<const bf16x8*>(vr);
                vf1[i] = *reinterpret_cast<const bf16x8*>(vr + 32);
            }

            f32x4 sfr[2][4];
            __builtin_amdgcn_s_setprio(1);
            #pragma unroll
            for (int f = 0; f < 4; f++) {
                #pragma unroll
                for (int b = 0; b < 2; b++) {
                    f32x4 acc = (f32x4){0.f, 0.f, 0.f, 0.f};
                    acc = __builtin_amdgcn_mfma_f32_16x16x32_bf16(kf0[f], qf0[b], acc, 0, 0, 0);
                    acc = __builtin_amdgcn_mfma_f32_16x16x32_bf16(kf1[f], qf1[b], acc, 0, 0, 0);
                    sfr[b][f] = acc;
                }
            }
            __builtin_amdgcn_s_setprio(0);

            float rmax[2] = {-INFINITY, -INFINITY};
            if (!needmask) {
                #pragma unroll
                for (int f = 0; f < 4; f++)
                    #pragma unroll
                    for (int b = 0; b < 2; b++)
                        #pragma unroll
                        for (int r = 0; r < 4; r++) rmax[b] = fmaxf(rmax[b], sfr[b][f][r]);
            } else {
                #pragma unroll
                for (int f = 0; f < 4; f++)
                    #pragma unroll
                    for (int r = 0; r < 4; r++) {
                        int key = kbase + f * 16 + lg * 4 + r;
                        #pragma unroll
                        for (int b = 0; b < 2; b++) {
                            int lim = (key < 3000) ? limp[b] : ((key < 3300) ? limb[b] : limc[b]);
                            float v = sfr[b][f][r];
                            v = (key <= lim) ? v : -INFINITY;
                            sfr[b][f][r] = v;
                            rmax[b] = fmaxf(rmax[b], v);
                        }
                    }
            }
            if (!qok[0]) rmax[0] = -INFINITY;
            if (!qok[1]) rmax[1] = -INFINITY;
            #pragma unroll
            for (int b = 0; b < 2; b++) {
                rmax[b] = fmaxf(rmax[b], __shfl_xor(rmax[b], 16));
                rmax[b] = fmaxf(rmax[b], __shfl_xor(rmax[b], 32));
            }
            bool upd = (rmax[0] > m[0] + 8.f) || (rmax[1] > m[1] + 8.f);
            if (__any(upd)) {
                #pragma unroll
                for (int b = 0; b < 2; b++) {
                    float mn2 = fmaxf(m[b], rmax[b]);
                    float c = (m[b] == -INFINITY) ? 0.f : exp2f(m[b] - mn2);
                    m[b] = mn2;
                    ls[b] *= c;
                    f32x4 cv;
                    cv[0] = __shfl(c, lg * 4 + 0);
                    cv[1] = __shfl(c, lg * 4 + 1);
                    cv[2] = __shfl(c, lg * 4 + 2);
                    cv[3] = __shfl(c, lg * 4 + 3);
                    #pragma unroll
                    for (int i = 0; i < 4; i++) {
                        oacc[b][i][0] *= cv[0]; oacc[b][i][1] *= cv[1];
                        oacc[b][i][2] *= cv[2]; oacc[b][i][3] *= cv[3];
                    }
                }
            }
            if (!needmask) {
                #pragma unroll
                for (int b = 0; b < 2; b++)
                    #pragma unroll
                    for (int f = 0; f < 4; f++) {
                        float p0 = exp2f(sfr[b][f][0] - m[b]);
                        float p1 = exp2f(sfr[b][f][1] - m[b]);
                        float p2 = exp2f(sfr[b][f][2] - m[b]);
                        float p3 = exp2f(sfr[b][f][3] - m[b]);
                        ls[b] += (p0 + p1) + (p2 + p3);
                        *reinterpret_cast<u32*>(&plds[b][ll][f * 16 + lg * 4])     = cvt_pk_bf16(p0, p1);
                        *reinterpret_cast<u32*>(&plds[b][ll][f * 16 + lg * 4 + 2]) = cvt_pk_bf16(p2, p3);
                    }
            } else {
                #pragma unroll
                for (int b = 0; b < 2; b++)
                    #pragma unroll
                    for (int f = 0; f < 4; f++) {
                        float sv0 = sfr[b][f][0], sv1 = sfr[b][f][1];
                        float sv2 = sfr[b][f][2], sv3 = sfr[b][f][3];
                        float p0 = (sv0 == -INFINITY) ? 0.f : exp2f(sv0 - m[b]);
                        float p1 = (sv1 == -INFINITY) ? 0.f : exp2f(sv1 - m[b]);
                        float p2 = (sv2 == -INFINITY) ? 0.f : exp2f(sv2 - m[b]);
                        float p3 = (sv3 == -INFINITY) ? 0.f : exp2f(sv3 - m[b]);
                        ls[b] += (p0 + p1) + (p2 + p3);
                        *reinterpret_cast<u32*>(&plds[b][ll][f * 16 + lg * 4])     = cvt_pk_bf16(p0, p1);
                        *reinterpret_cast<u32*>(&plds[b][ll][f * 16 + lg * 4 + 2]) = cvt_pk_bf16(p2, p3);
                    }
            }
            __builtin_amdgcn_s_setprio(1);
            #pragma unroll
            for (int b = 0; b < 2; b++) {
                bf16x8 pf0 = *reinterpret_cast<const bf16x8*>(&plds[b][ll][lg * 8]);
                #pragma unroll
                for (int i = 0; i < 4; i++)
                    oacc[b][i] = __builtin_amdgcn_mfma_f32_16x16x32_bf16(pf0, vf0[i], oacc[b][i], 0, 0, 0);
                bf16x8 pf1 = *reinterpret_cast<const bf16x8*>(&plds[b][ll][32 + lg * 8]);
                #pragma unroll
                for (int i = 0; i < 4; i++)
                    oacc[b][i] = __builtin_amdgcn_mfma_f32_16x16x32_bf16(pf1, vf1[i], oacc[b][i], 0, 0, 0);
            }
            __builtin_amdgcn_s_setprio(0);
        }

        #pragma unroll
        for (int b = 0; b < 2; b++) {
            ls[b] += __shfl_xor(ls[b], 16);
            ls[b] += __shfl_xor(ls[b], 32);
        }
        u16* Ob = (z < 5) ? (Op0 + (size_t)z * ZSLICE) : (Op1 + (size_t)(z - 5) * ZSLICE);
        #pragma unroll
        for (int b = 0; b < 2; b++)
            #pragma unroll
            for (int r = 0; r < 4; r++) {
                int q = q0 + b * 16 + lg * 4 + r;
                if (q >= T_TOK) continue;
                size_t ob = ((size_t)h * 3600 + q) * 64;
                #pragma unroll
                for (int i = 0; i < 4; i++)
                    Ob[ob + i * 16 + ll] = f2bf(oacc[b][i][r]);
            }
        if (lg == 0) {
            #pragma unroll
            for (int b = 0; b < 2; b++) {
                int qa = q0 + b * 16 + ll;
                if (qa < T_TOK) {
                    size_t mi = ((size_t)(z * 8 + h) * 3600 + qa) * 2;
                    mlpart[mi]     = m[b];
                    mlpart[mi + 1] = ls[b];
                }
            }
        }
    }
}

// ---------------- merge KSPLIT partials -> obb (vectorized) ----------------
__global__ __launch_bounds__(256) void attn_merge_kernel(
    const u16* __restrict__ Op0, const u16* __restrict__ Op1,
    const float* __restrict__ mlpart, u16* __restrict__ obb)
{
    int t = threadIdx.x;
    int h = blockIdx.y;
    int q = blockIdx.x * 64 + (t >> 2);
    if (q >= T_TOK) return;
    int dg = (t & 3) * 16;
    float mz[KSPLIT], lz[KSPLIT];
    #pragma unroll
    for (int zz = 0; zz < KSPLIT; zz++) {
        size_t mi = ((size_t)(zz * 8 + h) * 3600 + q) * 2;
        mz[zz] = mlpart[mi];
        lz[zz] = mlpart[mi + 1];
    }
    float M = -INFINITY;
    #pragma unroll
    for (int zz = 0; zz < KSPLIT; zz++) if (lz[zz] > 0.f) M = fmaxf(M, mz[zz]);
    float wz[KSPLIT], den = 0.f;
    #pragma unroll
    for (int zz = 0; zz < KSPLIT; zz++) {
        wz[zz] = (lz[zz] > 0.f) ? exp2f(mz[zz] - M) : 0.f;
        den += wz[zz] * lz[zz];
    }
    float inv = (den > 0.f) ? 1.f / den : 0.f;
    size_t qoff = ((size_t)h * 3600 + q) * 64 + dg;
    float acc[16];
    #pragma unroll
    for (int e = 0; e < 16; e++) acc[e] = 0.f;
    #pragma unroll
    for (int zz = 0; zz < KSPLIT; zz++) {
        const u16* Ob = (zz < 5) ? (Op0 + (size_t)zz * ZSLICE) : (Op1 + (size_t)(zz - 5) * ZSLICE);
        bf16x8 v0 = *reinterpret_cast<const bf16x8*>(Ob + qoff);
        bf16x8 v1 = *reinterpret_cast<const bf16x8*>(Ob + qoff + 8);
        float w = wz[zz];
        #pragma unroll
        for (int e = 0; e < 8; e++) {
            acc[e]     += bf2f((u16)v0[e]) * w;
            acc[8 + e] += bf2f((u16)v1[e]) * w;
        }
    }
    u16 o16[16];
    #pragma unroll
    for (int e = 0; e < 16; e++) o16[e] = f2bf(acc[e] * inv);
    u16* op = obb + (size_t)q * D_ + h * HD + dg;
    *reinterpret_cast<bf16x8*>(op)     = *reinterpret_cast<const bf16x8*>(&o16[0]);
    *reinterpret_cast<bf16x8*>(op + 8) = *reinterpret_cast<const bf16x8*>(&o16[8]);
}

// ---------------- residual add (two partials) + LayerNorm (float4) --------
__global__ __launch_bounds__(128) void add_ln3_kernel(
    float* __restrict__ x, const float* __restrict__ r1, const float* __restrict__ r2,
    const float* __restrict__ g, const float* __restrict__ b,
    u16* __restrict__ xb)
{
    int row = blockIdx.x, t = threadIdx.x;   // 128 threads, 4 elems each
    size_t base = (size_t)row * D_ + t * 4;
    float4 xv = *reinterpret_cast<const float4*>(&x[base]);
    float4 a1 = *reinterpret_cast<const float4*>(&r1[base]);
    float4 a2 = *reinterpret_cast<const float4*>(&r2[base]);
    float v0 = xv.x + a1.x + a2.x;
    float v1 = xv.y + a1.y + a2.y;
    float v2 = xv.z + a1.z + a2.z;
    float v3 = xv.w + a1.w + a2.w;
    float s = (v0 + v1) + (v2 + v3);
    float ss = (v0 * v0 + v1 * v1) + (v2 * v2 + v3 * v3);
    #pragma unroll
    for (int off = 32; off > 0; off >>= 1) {
        s  += __shfl_xor(s, off);
        ss += __shfl_xor(ss, off);
    }
    __shared__ float rs[2], rss[2];
    int w = t >> 6;
    if ((t & 63) == 0) { rs[w] = s; rss[w] = ss; }
    __syncthreads();
    s  = rs[0] + rs[1];
    ss = rss[0] + rss[1];
    float mean = s * (1.f / 512.f);
    float var = ss * (1.f / 512.f) - mean * mean;
    float rstd = rsqrtf(var + 1e-5f);
    float4 gv = *reinterpret_cast<const float4*>(&g[t * 4]);
    float4 bv = *reinterpret_cast<const float4*>(&b[t * 4]);
    float o0 = (v0 - mean) * rstd * gv.x + bv.x;
    float o1 = (v1 - mean) * rstd * gv.y + bv.y;
    float o2 = (v2 - mean) * rstd * gv.z + bv.z;
    float o3 = (v3 - mean) * rstd * gv.w + bv.w;
    *reinterpret_cast<float4*>(&x[base]) = make_float4(o0, o1, o2, o3);
    ushort4 ob;
    ob.x = f2bf(o0); ob.y = f2bf(o1); ob.z = f2bf(o2); ob.w = f2bf(o3);
    *reinterpret_cast<ushort4*>(&xb[base]) = ob;
}

// ---------------------------------------------------------------------------
extern "C" void kernel_launch(void* const* d_in, const int* in_sizes, int n_in,
                              void* d_out, int out_size, void* d_ws, size_t ws_size,
                              hipStream_t stream)
{
    const float* player_xs = (const float*)d_in[0];
    const float* player_ys = (const float*)d_in[1];
    const float* player_hs = (const float*)d_in[2];
    const float* ball_xs   = (const float*)d_in[3];
    const float* ball_ys   = (const float*)d_in[4];
    const float* ball_zs   = (const float*)d_in[5];
    const float* emb_table = (const float*)d_in[6];
    const float* ball_emb  = (const float*)d_in[7];
    const float* cls_emb   = (const float*)d_in[8];
    const float* pW0 = (const float*)d_in[9];   const float* pb0 = (const float*)d_in[10];
    const float* pW1 = (const float*)d_in[11];  const float* pb1 = (const float*)d_in[12];
    const float* pW2 = (const float*)d_in[13];  const float* pb2 = (const float*)d_in[14];
    const float* bW0 = (const float*)d_in[15];  const float* bb0 = (const float*)d_in[16];
    const float* bW1 = (const float*)d_in[17];  const float* bb1 = (const float*)d_in[18];
    const float* bW2 = (const float*)d_in[19];  const float* bb2 = (const float*)d_in[20];
    const float* Wqkv = (const float*)d_in[21]; const float* bqkv = (const float*)d_in[22];
    const float* Wo  = (const float*)d_in[23];  const float* bo  = (const float*)d_in[24];
    const float* W1f = (const float*)d_in[25];  const float* b1f = (const float*)d_in[26];
    const float* W2f = (const float*)d_in[27];  const float* b2f = (const float*)d_in[28];
    const float* g1  = (const float*)d_in[29];  const float* be1 = (const float*)d_in[30];
    const float* g2  = (const float*)d_in[31];  const float* be2 = (const float*)d_in[32];
    const float* cpW = (const float*)d_in[33];  const float* cpb = (const float*)d_in[34];
    const float* cbW = (const float*)d_in[35];  const float* cbb = (const float*)d_in[36];
    const float* csW = (const float*)d_in[37];  const float* csb = (const float*)d_in[38];
    const int* pidx = (const int*)d_in[39];

    // workspace (51.6 MB): x | big | obr | tmp2
    float* x    = (float*)d_ws;            // 1,843,200 f32
    float* big  = x + 1843200;             // 7,372,800 f32
    float* obr  = big + 7372800;           // 1,843,200 f32
    float* tmp2 = obr + 1843200;           // 1,843,200 f32
    u16*   qkvb   = (u16*)big;             // [3600][1024] bf16 (Q|K, compact)
    u16*   Op0    = (u16*)(big + 2764800); // z-slices 0-4
    u16*   wbh    = (u16*)(big + 6681600); // head weights bf16
    float* bhead  = big + 7100000;         // packed head bias
    u16*   ff1b   = (u16*)big;             // [3600][2048] bf16 (FF phase)
    float* r2buf  = big + 4000000;         // split-K second partial
    u16*   obb    = (u16*)obr;             // [3600][512] bf16
    u16*   xb     = (u16*)(obr + 921600);  // [3600][512] bf16
    u16*   vt     = (u16*)tmp2;            // [512][3648] bf16
    float* mlpart = tmp2 + 1000000;        // [8][8][3600][2] f32
    float* out = (float*)d_out;
    u16* wpack  = (u16*)d_out;
    u16* wqkv_b = wpack;                   // 1536*512
    u16* wo_b   = wpack + 786432;          // 512*512
    u16* w1f_b  = wpack + 1048576;         // 2048*512
    u16* w2f_b  = wpack + 2097152;         // 512*2048
    u16* Op1    = wpack + 3145728;         // z-slices 5-7
    float* IN = big;                       // 3600*24
    float* h0 = big + 131072;              // 3600*128
    float* h1 = big + 131072 + 460800;     // 3600*256

    gather_kernel<<<15, 256, 0, stream>>>(
        player_xs, player_ys, player_hs, ball_xs, ball_ys, ball_zs,
        emb_table, ball_emb, cls_emb, pidx, IN, x, xb);

    gemm_tok<1,0><<<dim3(24, 1, 2), 256, 0, stream>>>(
        IN, pW0, pb0, h0, IN + 3000*24, bW0, bb0, h0 + 3000*128, nullptr,
        3000, 300, 128, 23, 24, 1.f);
    gemm_tok<1,0><<<dim3(24, 2, 2), 256, 0, stream>>>(
        h0, pW1, pb1, h1, h0 + 3000*128, bW1, bb1, h1 + 3000*256, nullptr,
        3000, 300, 256, 128, 128, 1.f);
    gemm_tok<0,1><<<dim3(24, 4, 2), 256, 0, stream>>>(
        h1, pW2, pb2, x, h1 + 3000*256, bW2, bb2, x + 3000*512, xb,
        3000, 300, 512, 256, 256, SQRT512);

    for (int l = 0; l < 4; l++) {
        const float* Wqkv_l = Wqkv + (size_t)l * 1536 * 512;
        const float* bqkv_l = bqkv + (size_t)l * 1536;
        const float* bo_l   = bo   + (size_t)l * 512;
        const float* Wo_l   = Wo   + (size_t)l * 512 * 512;
        const float* W1f_l  = W1f  + (size_t)l * 2048 * 512;
        const float* b1f_l  = b1f  + (size_t)l * 2048;
        const float* W2f_l  = W2f  + (size_t)l * 512 * 2048;
        const float* b2f_l  = b2f  + (size_t)l * 512;

        w2b4_kernel<<<1024, 256, 0, stream>>>(Wqkv_l, Wo_l, W1f_l, W2f_l, wpack, vt);
        gemm_async<0,1,1,0,0,1><<<dim3(29, 12), 256, 0, stream>>>(xb, wqkv_b, bqkv_l, qkvb, nullptr, vt, 3600, 1536, 512, 512, 1.f);
        attn_mfma_kernel<<<57 * 8 * 8, 64, 0, stream>>>(qkvb, vt, Op0, Op1, mlpart);
        attn_merge_kernel<<<dim3(57, 8), 256, 0, stream>>>(Op0, Op1, mlpart, obb);
        gemm_async<0,0,0,1,0,0><<<dim3(29, 4, 2), 256, 0, stream>>>(obb, wo_b, bo_l, tmp2, r2buf, nullptr, 3600, 512, 512, 512, 1.f);
        add_ln3_kernel<<<3600, 128, 0, stream>>>(x, tmp2, r2buf, g1 + (size_t)l * 512, be1 + (size_t)l * 512, xb);
        gemm_async<1,1,0,0,0,0><<<dim3(29, 16), 256, 0, stream>>>(xb, w1f_b, b1f_l, ff1b, nullptr, nullptr, 3600, 2048, 512, 512, 1.f);
        gemm_async<0,0,0,1,0,0><<<dim3(29, 4, 2), 256, 0, stream>>>(ff1b, w2f_b, b2f_l, tmp2, r2buf, nullptr, 3600, 512, 2048, 2048, 1.f);
        add_ln3_kernel<<<3600, 128, 0, stream>>>(x, tmp2, r2buf, g2 + (size_t)l * 512, be2 + (size_t)l * 512, xb);
    }

    w2bh_kernel<<<732, 256, 0, stream>>>(cpW, cbW, csW, cpb, cbb, csb, wbh, bhead);
    gemm_async<0,0,0,0,1,0><<<dim3(29, 12), 256, 0, stream>>>(xb, wbh, bhead, out, nullptr, nullptr, 3600, 1462, 512, 512, 1.f);
}

// Round 22
// 839.139 us; speedup vs baseline: 1.1460x; 1.0387x over previous
//
#include <hip/hip_runtime.h>
#include <hip/hip_bf16.h>

typedef unsigned short u16;
typedef unsigned int u32;
typedef __attribute__((ext_vector_type(8))) short bf16x8;
typedef __attribute__((ext_vector_type(4))) float f32x4;

#define T_TOK 3600
#define D_    512
#define H_    8
#define HD    64
#define NKT   57
#define VT_S  3648
#define KSPLIT 8
#define ZSLICE 1843200  // u16 per z-slice: 8*3600*64
#define QKS   1024      // qkvb row stride (Q|K only)
#define SQRT512 22.627416997969522f
#define QK_SCALE 0.18033688011112042f // 0.125 * log2(e)

__device__ __forceinline__ u16 f2bf(float f) {
    unsigned int x = __float_as_uint(f);
    unsigned int lsb = (x >> 16) & 1;
    return (u16)((x + 0x7fffu + lsb) >> 16);
}
__device__ __forceinline__ float bf2f(u16 u) {
    return __uint_as_float(((unsigned int)u) << 16);
}
__device__ __forceinline__ u32 cvt_pk_bf16(float a, float b) {
    u32 r;
    asm("v_cvt_pk_bf16_f32 %0, %1, %2" : "=v"(r) : "v"(a), "v"(b));
    return r;
}
__device__ __forceinline__ void async_ld16(const void* g, void* l) {
    __builtin_amdgcn_global_load_lds(
        (const __attribute__((address_space(1))) void*)g,
        (__attribute__((address_space(3))) void*)l, 16, 0, 0);
}
__device__ __forceinline__ int step_of(int i) {
    return (i < 3000) ? (i / 10) : ((i < 3300) ? (i - 3000) : (i - 3300));
}
__device__ __forceinline__ void tile_minmax(int kbase, int& mn, int& mx) {
    int a = kbase, b = min(kbase + 63, T_TOK - 1);
    mn = 0x7fffffff; mx = -1;
    if (a < 3000)              { mn = min(mn, a / 10);              mx = max(mx, min(b, 2999) / 10); }
    if (b >= 3000 && a < 3300) { mn = min(mn, max(a, 3000) - 3000); mx = max(mx, min(b, 3299) - 3000); }
    if (b >= 3300)             { mn = min(mn, max(a, 3300) - 3300); mx = max(mx, b - 3300); }
}

// ---------------- gather: IN[3600][24] + cls rows of x and xb --------------
__global__ __launch_bounds__(256) void gather_kernel(
    const float* __restrict__ pxs, const float* __restrict__ pys, const float* __restrict__ phs,
    const float* __restrict__ bxs, const float* __restrict__ bys, const float* __restrict__ bzs,
    const float* __restrict__ emb_table, const float* __restrict__ ball_emb,
    const float* __restrict__ cls_emb, const int* __restrict__ pidx,
    float* __restrict__ IN, float* __restrict__ x, u16* __restrict__ xb)
{
    int g = blockIdx.x * 256 + threadIdx.x;
    if (g < 3300) {
        float* row = IN + g * 24;
        if (g < 3000) {
            int id = pidx[g];
            #pragma unroll
            for (int e = 0; e < 20; e++) row[e] = emb_table[id * 20 + e];
            row[20] = pxs[g]; row[21] = pys[g]; row[22] = phs[g];
        } else {
            int b = g - 3000;
            #pragma unroll
            for (int e = 0; e < 20; e++) row[e] = ball_emb[e];
            row[20] = bxs[b]; row[21] = bys[b]; row[22] = bzs[b];
        }
        row[23] = 0.f;
    }
    for (int i = g; i < 300 * 512; i += 3840) {
        float v = cls_emb[i & 511];
        x[3300 * 512 + i] = v;
        xb[3300 * 512 + i] = f2bf(v);
    }
}

// ---------------- per-layer weight convert + vt-pad zero -------------------
__global__ __launch_bounds__(256) void w2b4_kernel(
    const float* __restrict__ s0, const float* __restrict__ s1,
    const float* __restrict__ s2, const float* __restrict__ s3,
    u16* __restrict__ dst, u16* __restrict__ vt)
{
    int stride = gridDim.x * 256;
    for (int i = blockIdx.x * 256 + threadIdx.x; i < 786432; i += stride) {
        const float4* src;
        int j = i;
        if (j < 196608)      { src = (const float4*)s0; }
        else if (j < 262144) { src = (const float4*)s1; j -= 196608; }
        else if (j < 524288) { src = (const float4*)s2; j -= 262144; }
        else                 { src = (const float4*)s3; j -= 524288; }
        float4 v = src[j];
        ushort4 o;
        o.x = f2bf(v.x); o.y = f2bf(v.y); o.z = f2bf(v.z); o.w = f2bf(v.w);
        reinterpret_cast<ushort4*>(dst)[i] = o;
    }
    // zero vt's pad tokens [3600,3648) on all 512 rows
    for (int i = blockIdx.x * 256 + threadIdx.x; i < 512 * 64; i += stride) {
        int row = i >> 6, c = i & 63;
        if (c < 48) vt[(size_t)row * VT_S + 3600 + c] = 0;
    }
}

// ---------------- head-weight + bias pack ----------------------------------
__global__ __launch_bounds__(256) void w2bh_kernel(
    const float* __restrict__ cp, const float* __restrict__ cb,
    const float* __restrict__ cs, const float* __restrict__ bp,
    const float* __restrict__ bb, const float* __restrict__ bs,
    u16* __restrict__ dst, float* __restrict__ bias)
{
    int stride = gridDim.x * 256;
    for (int i = blockIdx.x * 256 + threadIdx.x; i < 187136; i += stride) {
        const float4* src;
        int j = i;
        if (j < 15488)       { src = (const float4*)cp; }
        else if (j < 185856) { src = (const float4*)cb; j -= 15488; }
        else                 { src = (const float4*)cs; j -= 185856; }
        float4 v = src[j];
        ushort4 o;
        o.x = f2bf(v.x); o.y = f2bf(v.y); o.z = f2bf(v.z); o.w = f2bf(v.w);
        reinterpret_cast<ushort4*>(dst)[i] = o;
    }
    int g = blockIdx.x * 256 + threadIdx.x;
    if (g < 1462)
        bias[g] = (g < 121) ? bp[g] : (g < 1452) ? bb[g - 121] : bs[g - 1452];
}

// ---------------- fp32-input token GEMM: player(z=0) / ball(z=1) ----------
__device__ __forceinline__ void stage_f32(
    const float* __restrict__ src, int nrows, int K, int lda,
    int r0, int kk, int srow, int scg, u16* dst)
{
    u16 tmp[16];
    int rr = r0 + srow;
    if (rr < nrows) {
        if (((lda & 3) == 0) && (kk + scg + 16 <= K)) {
            const float4* p = reinterpret_cast<const float4*>(src + (size_t)rr * lda + kk + scg);
            #pragma unroll
            for (int q = 0; q < 4; q++) {
                float4 v = p[q];
                tmp[q*4+0] = f2bf(v.x); tmp[q*4+1] = f2bf(v.y);
                tmp[q*4+2] = f2bf(v.z); tmp[q*4+3] = f2bf(v.w);
            }
        } else {
            #pragma unroll
            for (int e = 0; e < 16; e++) {
                int kc = kk + scg + e;
                tmp[e] = (kc < K) ? f2bf(src[(size_t)rr * lda + kc]) : (u16)0;
            }
        }
    } else {
        #pragma unroll
        for (int e = 0; e < 16; e++) tmp[e] = 0;
    }
    *reinterpret_cast<bf16x8*>(dst)     = *reinterpret_cast<const bf16x8*>(&tmp[0]);
    *reinterpret_cast<bf16x8*>(dst + 8) = *reinterpret_cast<const bf16x8*>(&tmp[8]);
}

template<int RELU, int DUAL>
__global__ __launch_bounds__(256) void gemm_tok(
    const float* __restrict__ A0, const float* __restrict__ W0p,
    const float* __restrict__ b0p, float* __restrict__ C0,
    const float* __restrict__ A1, const float* __restrict__ W1p,
    const float* __restrict__ b1p, float* __restrict__ C1,
    u16* __restrict__ Cb,
    int M0, int M1, int N, int K, int lda, float scale)
{
    int zz = blockIdx.z;
    int M = zz ? M1 : M0;
    int m0 = blockIdx.x * 128;
    if (m0 >= M) return;
    const float* A = zz ? A1 : A0;
    const float* W = zz ? W1p : W0p;
    const float* bias = zz ? b1p : b0p;
    float* C = zz ? C1 : C0;
    u16* CbL = DUAL ? (zz ? Cb + (size_t)M0 * N : Cb) : nullptr;

    __shared__ u16 As[128][40];
    __shared__ u16 Bs[128][40];
    int t = threadIdx.x;
    int w = t >> 6, l = t & 63;
    int ll = l & 15, lg = l >> 4;
    int wr = w >> 1, wc = w & 1;
    int n0 = blockIdx.y * 128;
    int srow = t >> 1;
    int scg  = (t & 1) * 16;

    f32x4 acc[4][4];
    #pragma unroll
    for (int i = 0; i < 4; i++)
        #pragma unroll
        for (int j = 0; j < 4; j++) acc[i][j] = (f32x4){0.f, 0.f, 0.f, 0.f};

    for (int kk = 0; kk < K; kk += 32) {
        stage_f32(A, M, K, lda, m0, kk, srow, scg, &As[srow][scg]);
        stage_f32(W, N, K, K, n0, kk, srow, scg, &Bs[srow][scg]);
        __syncthreads();
        bf16x8 af[4], bf[4];
        #pragma unroll
        for (int i = 0; i < 4; i++)
            af[i] = *reinterpret_cast<const bf16x8*>(&As[wr*64 + i*16 + ll][lg*8]);
        #pragma unroll
        for (int j = 0; j < 4; j++)
            bf[j] = *reinterpret_cast<const bf16x8*>(&Bs[wc*64 + j*16 + ll][lg*8]);
        #pragma unroll
        for (int i = 0; i < 4; i++)
            #pragma unroll
            for (int j = 0; j < 4; j++)
                acc[i][j] = __builtin_amdgcn_mfma_f32_16x16x32_bf16(af[i], bf[j], acc[i][j], 0, 0, 0);
        __syncthreads();
    }

    float bv[4];
    #pragma unroll
    for (int j = 0; j < 4; j++) {
        int n = n0 + wc*64 + j*16 + ll;
        bv[j] = (n < N) ? bias[n] : 0.f;
    }
    #pragma unroll
    for (int i = 0; i < 4; i++) {
        #pragma unroll
        for (int r = 0; r < 4; r++) {
            int m = m0 + wr*64 + i*16 + lg*4 + r;
            if (m >= M) continue;
            #pragma unroll
            for (int j = 0; j < 4; j++) {
                int n = n0 + wc*64 + j*16 + ll;
                if (n >= N) continue;
                float v = acc[i][j][r] + bv[j];
                if (RELU) v = fmaxf(v, 0.f);
                v *= scale;
                C[(size_t)m * N + n] = v;
                if (DUAL) CbL[(size_t)m * N + n] = f2bf(v);
            }
        }
    }
}

// ---------------- bf16 MFMA GEMM, 2-phase pipelined global_load_lds --------
template<int RELU, int BF16OUT, int QSCALE, int SPLITK, int HEADS, int VTOUT>
__global__ __launch_bounds__(256) void gemm_async(
    const u16* __restrict__ A, const u16* __restrict__ W,
    const float* __restrict__ bias, void* __restrict__ Cv, float* __restrict__ C1,
    u16* __restrict__ vtp, int M, int N, int K, int lda, float scale)
{
    __shared__ u16 As[2][4096];   // [buf][128][32]
    __shared__ u16 Bs[2][4096];
    int t = threadIdx.x;
    int w = t >> 6, l = t & 63;
    int ll = l & 15, lg = l >> 4;
    int wr = w >> 1, wc = w & 1;
    int m0 = blockIdx.x * 128, n0 = blockIdx.y * 128;
    int srow = l >> 2;
    int skg  = (l & 3) * 8;
    int kz = SPLITK ? blockIdx.z : 0;
    int khalf = SPLITK ? (K >> 1) : K;
    int kbeg = kz * khalf;
    int nt = khalf >> 5;   // K-steps of 32

    const u16* pa0 = A + (size_t)min(m0 + w * 16 + srow, M - 1) * lda + skg;
    const u16* pa1 = A + (size_t)min(m0 + 64 + w * 16 + srow, M - 1) * lda + skg;
    const u16* pb0 = W + (size_t)min(n0 + w * 16 + srow, N - 1) * K + skg;
    const u16* pb1 = W + (size_t)min(n0 + 64 + w * 16 + srow, N - 1) * K + skg;
    int la0 = (w * 16) * 32;
    int la1 = (64 + w * 16) * 32;

    f32x4 acc[4][4];
    #pragma unroll
    for (int i = 0; i < 4; i++)
        #pragma unroll
        for (int j = 0; j < 4; j++) acc[i][j] = (f32x4){0.f, 0.f, 0.f, 0.f};

    // prologue: stage tile 0 into buf 0
    async_ld16(pa0 + kbeg, &As[0][la0]);
    async_ld16(pa1 + kbeg, &As[0][la1]);
    async_ld16(pb0 + kbeg, &Bs[0][la0]);
    async_ld16(pb1 + kbeg, &Bs[0][la1]);
    __syncthreads();

    int cur = 0;
    for (int it = 0; it < nt; ++it) {
        int kk = kbeg + (it << 5);
        if (it + 1 < nt) {   // prefetch next tile into buf^1 (hidden under MFMA)
            int kn = kk + 32;
            async_ld16(pa0 + kn, &As[cur ^ 1][la0]);
            async_ld16(pa1 + kn, &As[cur ^ 1][la1]);
            async_ld16(pb0 + kn, &Bs[cur ^ 1][la0]);
            async_ld16(pb1 + kn, &Bs[cur ^ 1][la1]);
        }
        bf16x8 af[4], bf[4];
        #pragma unroll
        for (int i = 0; i < 4; i++)
            af[i] = *reinterpret_cast<const bf16x8*>(&As[cur][(wr*64 + i*16 + ll) * 32 + lg*8]);
        #pragma unroll
        for (int j = 0; j < 4; j++)
            bf[j] = *reinterpret_cast<const bf16x8*>(&Bs[cur][(wc*64 + j*16 + ll) * 32 + lg*8]);
        #pragma unroll
        for (int i = 0; i < 4; i++)
            #pragma unroll
            for (int j = 0; j < 4; j++)
                acc[i][j] = __builtin_amdgcn_mfma_f32_16x16x32_bf16(af[i], bf[j], acc[i][j], 0, 0, 0);
        __syncthreads();   // drains prefetch vmcnt; all reads of buf[cur] done
        cur ^= 1;
    }

    float bv[4];
    #pragma unroll
    for (int j = 0; j < 4; j++) {
        int n = n0 + wc*64 + j*16 + ll;
        bv[j] = (n < N && (!SPLITK || kz == 0)) ? bias[n] : 0.f;
    }
    #pragma unroll
    for (int i = 0; i < 4; i++) {
        if (VTOUT) {
            #pragma unroll
            for (int j = 0; j < 4; j++) {
                int n = n0 + wc*64 + j*16 + ll;
                int mb = m0 + wr*64 + i*16 + lg*4;
                if (n >= 1024) {
                    if (mb < T_TOK) {
                        ushort4 o;
                        o.x = f2bf(acc[i][j][0] + bv[j]);
                        o.y = f2bf(acc[i][j][1] + bv[j]);
                        o.z = f2bf(acc[i][j][2] + bv[j]);
                        o.w = f2bf(acc[i][j][3] + bv[j]);
                        *reinterpret_cast<ushort4*>(vtp + (size_t)(n - 1024) * VT_S + mb) = o;
                    }
                } else {
                    #pragma unroll
                    for (int r = 0; r < 4; r++) {
                        int mm = mb + r;
                        if (mm >= M) continue;
                        float v = acc[i][j][r] + bv[j];
                        if (n < 512) v *= QK_SCALE;
                        ((u16*)Cv)[(size_t)mm * QKS + n] = f2bf(v);
                    }
                }
            }
        } else {
            #pragma unroll
            for (int r = 0; r < 4; r++) {
                int m = m0 + wr*64 + i*16 + lg*4 + r;
                if (m >= M) continue;
                #pragma unroll
                for (int j = 0; j < 4; j++) {
                    int n = n0 + wc*64 + j*16 + ll;
                    if (n >= N) continue;
                    float v = acc[i][j][r] + bv[j];
                    if (RELU) v = fmaxf(v, 0.f);
                    v *= scale;
                    if (QSCALE && n < 512) v *= QK_SCALE;
                    if (HEADS) {
                        float* o = (float*)Cv;
                        if (n < 121)       o[(size_t)m * 121 + n] = v;
                        else if (n < 1452) (o + 435600)[(size_t)m * 1331 + (n - 121)] = v;
                        else               (o + 5227200)[(size_t)m * 10 + (n - 1452)] = v;
                    } else if (SPLITK && kz == 1) {
                        C1[(size_t)m * N + n] = v;
                    } else if (BF16OUT) {
                        ((u16*)Cv)[(size_t)m * N + n] = f2bf(v);
                    } else {
                        ((float*)Cv)[(size_t)m * N + n] = v;
                    }
                }
            }
        }
    }
}

// ---------------- MFMA flash attention: 32 q/wave, swapped QK^T ------------
// grid 7232 = 113 ranks x 8 z x 8 heads (1 q-tile per wave; rank-major LPT).
// h = bid&7 pins head->XCD. qkvb row stride QKS=1024 (Q|K only).
__global__ __launch_bounds__(64) void attn_mfma_kernel(
    const u16* __restrict__ qkvb, const u16* __restrict__ vt,
    u16* __restrict__ Op0, u16* __restrict__ Op1, float* __restrict__ mlpart)
{
    __shared__ u16 plds[2][16][66];
    int l = threadIdx.x;
    int lg = l >> 4, ll = l & 15;
    int bid = blockIdx.x;
    int h = bid & 7;
    int rest = bid >> 3;      // 0..903
    int z = rest & 7;         // 0..7
    int rank = rest >> 3;     // 0..112 (rank-major: heavy q-tiles dispatch first)
    int q0 = (112 - rank) * 32;

    bf16x8 qf0[2], qf1[2];
    int sql[2];
    bool qok[2];
    #pragma unroll
    for (int b = 0; b < 2; b++) {
        int qa = q0 + b * 16 + ll;
        qok[b] = qa < T_TOK;
        int qac = min(qa, T_TOK - 1);
        const u16* qrow = qkvb + (size_t)qac * QKS + h * HD + lg * 8;
        qf0[b] = *reinterpret_cast<const bf16x8*>(qrow);
        qf1[b] = *reinterpret_cast<const bf16x8*>(qrow + 32);
        sql[b] = step_of(qac);
    }
    int sl = max(sql[0], sql[1]), s2 = min(sql[0], sql[1]);
    #pragma unroll
    for (int off = 1; off < 16; off <<= 1) {
        sl = max(sl, __shfl_xor(sl, off));
        s2 = min(s2, __shfl_xor(s2, off));
    }
    int smax = sl, smin = s2;
    int limp[2], limb[2], limc[2];
    #pragma unroll
    for (int b = 0; b < 2; b++) {
        limp[b] = sql[b] * 10 + 9;
        limb[b] = 3000 + sql[b];
        limc[b] = 3300 + sql[b];
    }

    f32x4 oacc[2][4];
    #pragma unroll
    for (int b = 0; b < 2; b++)
        #pragma unroll
        for (int i = 0; i < 4; i++) oacc[b][i] = (f32x4){0.f, 0.f, 0.f, 0.f};
    float m[2] = {-INFINITY, -INFINITY};
    float ls[2] = {0.f, 0.f};

    #pragma unroll 1
    for (int kt = z; kt < NKT; kt += KSPLIT) {
        int kbase = kt * 64;
        int mn, mx;
        tile_minmax(kbase, mn, mx);
        if (mn > smax) continue;
        bool needmask = (mx > smin) || (kbase + 64 > T_TOK);

        bf16x8 kf0[4], kf1[4];
        #pragma unroll
        for (int f = 0; f < 4; f++) {
            int keyc = min(kbase + f * 16 + ll, T_TOK - 1);
            const u16* kr = qkvb + (size_t)keyc * QKS + 512 + h * HD + lg * 8;
            kf0[f] = *reinterpret_cast<const bf16x8*>(kr);
            kf1[f] = *reinterpret_cast<const bf16x8*>(kr + 32);
        }
        bf16x8 vf0[4], vf1[4];
        #pragma unroll
        for (int i = 0; i < 4; i++) {
            const u16* vr = vt + (size_t)(h * HD + i * 16 + ll) * VT_S + kbase + lg * 8;
            vf0[i] = *reinterpret_cast<const bf16x8*>(vr);
            vf1[i] = *reinterpret_cast<const bf16x8*>(vr + 32);
        }

        f32x4 sfr[2][4];
        __builtin_amdgcn_s_setprio(1);
        #pragma unroll
        for (int f = 0; f < 4; f++) {
            #pragma unroll
            for (int b = 0; b < 2; b++) {
                f32x4 acc = (f32x4){0.f, 0.f, 0.f, 0.f};
                acc = __builtin_amdgcn_mfma_f32_16x16x32_bf16(kf0[f], qf0[b], acc, 0, 0, 0);
                acc = __builtin_amdgcn_mfma_f32_16x16x32_bf16(kf1[f], qf1[b], acc, 0, 0, 0);
                sfr[b][f] = acc;
            }
        }
        __builtin_amdgcn_s_setprio(0);

        float rmax[2] = {-INFINITY, -INFINITY};
        if (!needmask) {
            #pragma unroll
            for (int f = 0; f < 4; f++)
                #pragma unroll
                for (int b = 0; b < 2; b++)
                    #pragma unroll
                    for (int r = 0; r < 4; r++) rmax[b] = fmaxf(rmax[b], sfr[b][f][r]);
        } else {
            #pragma unroll
            for (int f = 0; f < 4; f++)
                #pragma unroll
                for (int r = 0; r < 4; r++) {
                    int key = kbase + f * 16 + lg * 4 + r;
                    #pragma unroll
                    for (int b = 0; b < 2; b++) {
                        int lim = (key < 3000) ? limp[b] : ((key < 3300) ? limb[b] : limc[b]);
                        float v = sfr[b][f][r];
                        v = (key <= lim) ? v : -INFINITY;
                        sfr[b][f][r] = v;
                        rmax[b] = fmaxf(rmax[b], v);
                    }
                }
        }
        if (!qok[0]) rmax[0] = -INFINITY;
        if (!qok[1]) rmax[1] = -INFINITY;
        #pragma unroll
        for (int b = 0; b < 2; b++) {
            rmax[b] = fmaxf(rmax[b], __shfl_xor(rmax[b], 16));
            rmax[b] = fmaxf(rmax[b], __shfl_xor(rmax[b], 32));
        }
        bool upd = (rmax[0] > m[0] + 8.f) || (rmax[1] > m[1] + 8.f);
        if (__any(upd)) {
            #pragma unroll
            for (int b = 0; b < 2; b++) {
                float mn2 = fmaxf(m[b], rmax[b]);
                float c = (m[b] == -INFINITY) ? 0.f : exp2f(m[b] - mn2);
                m[b] = mn2;
                ls[b] *= c;
                f32x4 cv;
                cv[0] = __shfl(c, lg * 4 + 0);
                cv[1] = __shfl(c, lg * 4 + 1);
                cv[2] = __shfl(c, lg * 4 + 2);
                cv[3] = __shfl(c, lg * 4 + 3);
                #pragma unroll
                for (int i = 0; i < 4; i++) {
                    oacc[b][i][0] *= cv[0]; oacc[b][i][1] *= cv[1];
                    oacc[b][i][2] *= cv[2]; oacc[b][i][3] *= cv[3];
                }
            }
        }
        if (!needmask) {
            #pragma unroll
            for (int b = 0; b < 2; b++)
                #pragma unroll
                for (int f = 0; f < 4; f++) {
                    float p0 = exp2f(sfr[b][f][0] - m[b]);
                    float p1 = exp2f(sfr[b][f][1] - m[b]);
                    float p2 = exp2f(sfr[b][f][2] - m[b]);
                    float p3 = exp2f(sfr[b][f][3] - m[b]);
                    ls[b] += (p0 + p1) + (p2 + p3);
                    *reinterpret_cast<u32*>(&plds[b][ll][f * 16 + lg * 4])     = cvt_pk_bf16(p0, p1);
                    *reinterpret_cast<u32*>(&plds[b][ll][f * 16 + lg * 4 + 2]) = cvt_pk_bf16(p2, p3);
                }
        } else {
            #pragma unroll
            for (int b = 0; b < 2; b++)
                #pragma unroll
                for (int f = 0; f < 4; f++) {
                    float sv0 = sfr[b][f][0], sv1 = sfr[b][f][1];
                    float sv2 = sfr[b][f][2], sv3 = sfr[b][f][3];
                    float p0 = (sv0 == -INFINITY) ? 0.f : exp2f(sv0 - m[b]);
                    float p1 = (sv1 == -INFINITY) ? 0.f : exp2f(sv1 - m[b]);
                    float p2 = (sv2 == -INFINITY) ? 0.f : exp2f(sv2 - m[b]);
                    float p3 = (sv3 == -INFINITY) ? 0.f : exp2f(sv3 - m[b]);
                    ls[b] += (p0 + p1) + (p2 + p3);
                    *reinterpret_cast<u32*>(&plds[b][ll][f * 16 + lg * 4])     = cvt_pk_bf16(p0, p1);
                    *reinterpret_cast<u32*>(&plds[b][ll][f * 16 + lg * 4 + 2]) = cvt_pk_bf16(p2, p3);
                }
        }
        __builtin_amdgcn_s_setprio(1);
        #pragma unroll
        for (int b = 0; b < 2; b++) {
            bf16x8 pf0 = *reinterpret_cast<const bf16x8*>(&plds[b][ll][lg * 8]);
            #pragma unroll
            for (int i = 0; i < 4; i++)
                oacc[b][i] = __builtin_amdgcn_mfma_f32_16x16x32_bf16(pf0, vf0[i], oacc[b][i], 0, 0, 0);
            bf16x8 pf1 = *reinterpret_cast<const bf16x8*>(&plds[b][ll][32 + lg * 8]);
            #pragma unroll
            for (int i = 0; i < 4; i++)
                oacc[b][i] = __builtin_amdgcn_mfma_f32_16x16x32_bf16(pf1, vf1[i], oacc[b][i], 0, 0, 0);
        }
        __builtin_amdgcn_s_setprio(0);
    }

    #pragma unroll
    for (int b = 0; b < 2; b++) {
        ls[b] += __shfl_xor(ls[b], 16);
        ls[b] += __shfl_xor(ls[b], 32);
    }
    u16* Ob = (z < 5) ? (Op0 + (size_t)z * ZSLICE) : (Op1 + (size_t)(z - 5) * ZSLICE);
    #pragma unroll
    for (int b = 0; b < 2; b++)
        #pragma unroll
        for (int r = 0; r < 4; r++) {
            int q = q0 + b * 16 + lg * 4 + r;
            if (q >= T_TOK) continue;
            size_t ob = ((size_t)h * 3600 + q) * 64;
            #pragma unroll
            for (int i = 0; i < 4; i++)
                Ob[ob + i * 16 + ll] = f2bf(oacc[b][i][r]);
        }
    if (lg == 0) {
        #pragma unroll
        for (int b = 0; b < 2; b++) {
            int qa = q0 + b * 16 + ll;
            if (qa < T_TOK) {
                size_t mi = ((size_t)(z * 8 + h) * 3600 + qa) * 2;
                mlpart[mi]     = m[b];
                mlpart[mi + 1] = ls[b];
            }
        }
    }
}

// ---------------- merge KSPLIT partials -> obb (vectorized) ----------------
__global__ __launch_bounds__(256) void attn_merge_kernel(
    const u16* __restrict__ Op0, const u16* __restrict__ Op1,
    const float* __restrict__ mlpart, u16* __restrict__ obb)
{
    int t = threadIdx.x;
    int h = blockIdx.y;
    int q = blockIdx.x * 64 + (t >> 2);
    if (q >= T_TOK) return;
    int dg = (t & 3) * 16;
    float mz[KSPLIT], lz[KSPLIT];
    #pragma unroll
    for (int zz = 0; zz < KSPLIT; zz++) {
        size_t mi = ((size_t)(zz * 8 + h) * 3600 + q) * 2;
        mz[zz] = mlpart[mi];
        lz[zz] = mlpart[mi + 1];
    }
    float M = -INFINITY;
    #pragma unroll
    for (int zz = 0; zz < KSPLIT; zz++) if (lz[zz] > 0.f) M = fmaxf(M, mz[zz]);
    float wz[KSPLIT], den = 0.f;
    #pragma unroll
    for (int zz = 0; zz < KSPLIT; zz++) {
        wz[zz] = (lz[zz] > 0.f) ? exp2f(mz[zz] - M) : 0.f;
        den += wz[zz] * lz[zz];
    }
    float inv = (den > 0.f) ? 1.f / den : 0.f;
    size_t qoff = ((size_t)h * 3600 + q) * 64 + dg;
    float acc[16];
    #pragma unroll
    for (int e = 0; e < 16; e++) acc[e] = 0.f;
    #pragma unroll
    for (int zz = 0; zz < KSPLIT; zz++) {
        const u16* Ob = (zz < 5) ? (Op0 + (size_t)zz * ZSLICE) : (Op1 + (size_t)(zz - 5) * ZSLICE);
        bf16x8 v0 = *reinterpret_cast<const bf16x8*>(Ob + qoff);
        bf16x8 v1 = *reinterpret_cast<const bf16x8*>(Ob + qoff + 8);
        float w = wz[zz];
        #pragma unroll
        for (int e = 0; e < 8; e++) {
            acc[e]     += bf2f((u16)v0[e]) * w;
            acc[8 + e] += bf2f((u16)v1[e]) * w;
        }
    }
    u16 o16[16];
    #pragma unroll
    for (int e = 0; e < 16; e++) o16[e] = f2bf(acc[e] * inv);
    u16* op = obb + (size_t)q * D_ + h * HD + dg;
    *reinterpret_cast<bf16x8*>(op)     = *reinterpret_cast<const bf16x8*>(&o16[0]);
    *reinterpret_cast<bf16x8*>(op + 8) = *reinterpret_cast<const bf16x8*>(&o16[8]);
}

// ---------------- residual add (two partials) + LayerNorm (float4) --------
__global__ __launch_bounds__(128) void add_ln3_kernel(
    float* __restrict__ x, const float* __restrict__ r1, const float* __restrict__ r2,
    const float* __restrict__ g, const float* __restrict__ b,
    u16* __restrict__ xb)
{
    int row = blockIdx.x, t = threadIdx.x;   // 128 threads, 4 elems each
    size_t base = (size_t)row * D_ + t * 4;
    float4 xv = *reinterpret_cast<const float4*>(&x[base]);
    float4 a1 = *reinterpret_cast<const float4*>(&r1[base]);
    float4 a2 = *reinterpret_cast<const float4*>(&r2[base]);
    float v0 = xv.x + a1.x + a2.x;
    float v1 = xv.y + a1.y + a2.y;
    float v2 = xv.z + a1.z + a2.z;
    float v3 = xv.w + a1.w + a2.w;
    float s = (v0 + v1) + (v2 + v3);
    float ss = (v0 * v0 + v1 * v1) + (v2 * v2 + v3 * v3);
    #pragma unroll
    for (int off = 32; off > 0; off >>= 1) {
        s  += __shfl_xor(s, off);
        ss += __shfl_xor(ss, off);
    }
    __shared__ float rs[2], rss[2];
    int w = t >> 6;
    if ((t & 63) == 0) { rs[w] = s; rss[w] = ss; }
    __syncthreads();
    s  = rs[0] + rs[1];
    ss = rss[0] + rss[1];
    float mean = s * (1.f / 512.f);
    float var = ss * (1.f / 512.f) - mean * mean;
    float rstd = rsqrtf(var + 1e-5f);
    float4 gv = *reinterpret_cast<const float4*>(&g[t * 4]);
    float4 bv = *reinterpret_cast<const float4*>(&b[t * 4]);
    float o0 = (v0 - mean) * rstd * gv.x + bv.x;
    float o1 = (v1 - mean) * rstd * gv.y + bv.y;
    float o2 = (v2 - mean) * rstd * gv.z + bv.z;
    float o3 = (v3 - mean) * rstd * gv.w + bv.w;
    *reinterpret_cast<float4*>(&x[base]) = make_float4(o0, o1, o2, o3);
    ushort4 ob;
    ob.x = f2bf(o0); ob.y = f2bf(o1); ob.z = f2bf(o2); ob.w = f2bf(o3);
    *reinterpret_cast<ushort4*>(&xb[base]) = ob;
}

// ---------------------------------------------------------------------------
extern "C" void kernel_launch(void* const* d_in, const int* in_sizes, int n_in,
                              void* d_out, int out_size, void* d_ws, size_t ws_size,
                              hipStream_t stream)
{
    const float* player_xs = (const float*)d_in[0];
    const float* player_ys = (const float*)d_in[1];
    const float* player_hs = (const float*)d_in[2];
    const float* ball_xs   = (const float*)d_in[3];
    const float* ball_ys   = (const float*)d_in[4];
    const float* ball_zs   = (const float*)d_in[5];
    const float* emb_table = (const float*)d_in[6];
    const float* ball_emb  = (const float*)d_in[7];
    const float* cls_emb   = (const float*)d_in[8];
    const float* pW0 = (const float*)d_in[9];   const float* pb0 = (const float*)d_in[10];
    const float* pW1 = (const float*)d_in[11];  const float* pb1 = (const float*)d_in[12];
    const float* pW2 = (const float*)d_in[13];  const float* pb2 = (const float*)d_in[14];
    const float* bW0 = (const float*)d_in[15];  const float* bb0 = (const float*)d_in[16];
    const float* bW1 = (const float*)d_in[17];  const float* bb1 = (const float*)d_in[18];
    const float* bW2 = (const float*)d_in[19];  const float* bb2 = (const float*)d_in[20];
    const float* Wqkv = (const float*)d_in[21]; const float* bqkv = (const float*)d_in[22];
    const float* Wo  = (const float*)d_in[23];  const float* bo  = (const float*)d_in[24];
    const float* W1f = (const float*)d_in[25];  const float* b1f = (const float*)d_in[26];
    const float* W2f = (const float*)d_in[27];  const float* b2f = (const float*)d_in[28];
    const float* g1  = (const float*)d_in[29];  const float* be1 = (const float*)d_in[30];
    const float* g2  = (const float*)d_in[31];  const float* be2 = (const float*)d_in[32];
    const float* cpW = (const float*)d_in[33];  const float* cpb = (const float*)d_in[34];
    const float* cbW = (const float*)d_in[35];  const float* cbb = (const float*)d_in[36];
    const float* csW = (const float*)d_in[37];  const float* csb = (const float*)d_in[38];
    const int* pidx = (const int*)d_in[39];

    // workspace (51.6 MB): x | big | obr | tmp2
    float* x    = (float*)d_ws;            // 1,843,200 f32
    float* big  = x + 1843200;             // 7,372,800 f32
    float* obr  = big + 7372800;           // 1,843,200 f32
    float* tmp2 = obr + 1843200;           // 1,843,200 f32
    u16*   qkvb   = (u16*)big;             // [3600][1024] bf16 (Q|K, compact)
    u16*   Op0    = (u16*)(big + 2764800); // z-slices 0-4
    u16*   wbh    = (u16*)(big + 6681600); // head weights bf16
    float* bhead  = big + 7100000;         // packed head bias
    u16*   ff1b   = (u16*)big;             // [3600][2048] bf16 (FF phase)
    float* r2buf  = big + 4000000;         // split-K second partial
    u16*   obb    = (u16*)obr;             // [3600][512] bf16
    u16*   xb     = (u16*)(obr + 921600);  // [3600][512] bf16
    u16*   vt     = (u16*)tmp2;            // [512][3648] bf16
    float* mlpart = tmp2 + 1000000;        // [8][8][3600][2] f32
    float* out = (float*)d_out;
    u16* wpack  = (u16*)d_out;
    u16* wqkv_b = wpack;                   // 1536*512
    u16* wo_b   = wpack + 786432;          // 512*512
    u16* w1f_b  = wpack + 1048576;         // 2048*512
    u16* w2f_b  = wpack + 2097152;         // 512*2048
    u16* Op1    = wpack + 3145728;         // z-slices 5-7
    float* IN = big;                       // 3600*24
    float* h0 = big + 131072;              // 3600*128
    float* h1 = big + 131072 + 460800;     // 3600*256

    gather_kernel<<<15, 256, 0, stream>>>(
        player_xs, player_ys, player_hs, ball_xs, ball_ys, ball_zs,
        emb_table, ball_emb, cls_emb, pidx, IN, x, xb);

    gemm_tok<1,0><<<dim3(24, 1, 2), 256, 0, stream>>>(
        IN, pW0, pb0, h0, IN + 3000*24, bW0, bb0, h0 + 3000*128, nullptr,
        3000, 300, 128, 23, 24, 1.f);
    gemm_tok<1,0><<<dim3(24, 2, 2), 256, 0, stream>>>(
        h0, pW1, pb1, h1, h0 + 3000*128, bW1, bb1, h1 + 3000*256, nullptr,
        3000, 300, 256, 128, 128, 1.f);
    gemm_tok<0,1><<<dim3(24, 4, 2), 256, 0, stream>>>(
        h1, pW2, pb2, x, h1 + 3000*256, bW2, bb2, x + 3000*512, xb,
        3000, 300, 512, 256, 256, SQRT512);

    for (int l = 0; l < 4; l++) {
        const float* Wqkv_l = Wqkv + (size_t)l * 1536 * 512;
        const float* bqkv_l = bqkv + (size_t)l * 1536;
        const float* bo_l   = bo   + (size_t)l * 512;
        const float* Wo_l   = Wo   + (size_t)l * 512 * 512;
        const float* W1f_l  = W1f  + (size_t)l * 2048 * 512;
        const float* b1f_l  = b1f  + (size_t)l * 2048;
        const float* W2f_l  = W2f  + (size_t)l * 512 * 2048;
        const float* b2f_l  = b2f  + (size_t)l * 512;

        w2b4_kernel<<<1024, 256, 0, stream>>>(Wqkv_l, Wo_l, W1f_l, W2f_l, wpack, vt);
        gemm_async<0,1,1,0,0,1><<<dim3(29, 12), 256, 0, stream>>>(xb, wqkv_b, bqkv_l, qkvb, nullptr, vt, 3600, 1536, 512, 512, 1.f);
        attn_mfma_kernel<<<113 * 8 * 8, 64, 0, stream>>>(qkvb, vt, Op0, Op1, mlpart);
        attn_merge_kernel<<<dim3(57, 8), 256, 0, stream>>>(Op0, Op1, mlpart, obb);
        gemm_async<0,0,0,1,0,0><<<dim3(29, 4, 2), 256, 0, stream>>>(obb, wo_b, bo_l, tmp2, r2buf, nullptr, 3600, 512, 512, 512, 1.f);
        add_ln3_kernel<<<3600, 128, 0, stream>>>(x, tmp2, r2buf, g1 + (size_t)l * 512, be1 + (size_t)l * 512, xb);
        gemm_async<1,1,0,0,0,0><<<dim3(29, 16), 256, 0, stream>>>(xb, w1f_b, b1f_l, ff1b, nullptr, nullptr, 3600, 2048, 512, 512, 1.f);
        gemm_async<0,0,0,1,0,0><<<dim3(29, 4, 2), 256, 0, stream>>>(ff1b, w2f_b, b2f_l, tmp2, r2buf, nullptr, 3600, 512, 2048, 2048, 1.f);
        add_ln3_kernel<<<3600, 128, 0, stream>>>(x, tmp2, r2buf, g2 + (size_t)l * 512, be2 + (size_t)l * 512, xb);
    }

    w2bh_kernel<<<732, 256, 0, stream>>>(cpW, cbW, csW, cpb, cbb, csb, wbh, bhead);
    gemm_async<0,0,0,0,1,0><<<dim3(29, 12), 256, 0, stream>>>(xb, wbh, bhead, out, nullptr, nullptr, 3600, 1462, 512, 512, 1.f);
}

// Round 23
// 831.442 us; speedup vs baseline: 1.1566x; 1.0093x over previous
//
#include <hip/hip_runtime.h>
#include <hip/hip_bf16.h>

typedef unsigned short u16;
typedef unsigned int u32;
typedef __attribute__((ext_vector_type(8))) short bf16x8;
typedef __attribute__((ext_vector_type(4))) float f32x4;

#define T_TOK 3600
#define D_    512
#define H_    8
#define HD    64
#define NKT   57
#define VT_S  3648
#define KSPLIT 8
#define ZSLICE 1843200  // u16 per z-slice: 8*3600*64
#define QKS   1024      // qkvb row stride (Q|K only)
#define SQRT512 22.627416997969522f
#define QK_SCALE 0.18033688011112042f // 0.125 * log2(e)

__device__ __forceinline__ u16 f2bf(float f) {
    unsigned int x = __float_as_uint(f);
    unsigned int lsb = (x >> 16) & 1;
    return (u16)((x + 0x7fffu + lsb) >> 16);
}
__device__ __forceinline__ float bf2f(u16 u) {
    return __uint_as_float(((unsigned int)u) << 16);
}
__device__ __forceinline__ u32 cvt_pk_bf16(float a, float b) {
    u32 r;
    asm("v_cvt_pk_bf16_f32 %0, %1, %2" : "=v"(r) : "v"(a), "v"(b));
    return r;
}
__device__ __forceinline__ void async_ld16(const void* g, void* l) {
    __builtin_amdgcn_global_load_lds(
        (const __attribute__((address_space(1))) void*)g,
        (__attribute__((address_space(3))) void*)l, 16, 0, 0);
}
__device__ __forceinline__ int step_of(int i) {
    return (i < 3000) ? (i / 10) : ((i < 3300) ? (i - 3000) : (i - 3300));
}
__device__ __forceinline__ void tile_minmax(int kbase, int& mn, int& mx) {
    int a = kbase, b = min(kbase + 63, T_TOK - 1);
    mn = 0x7fffffff; mx = -1;
    if (a < 3000)              { mn = min(mn, a / 10);              mx = max(mx, min(b, 2999) / 10); }
    if (b >= 3000 && a < 3300) { mn = min(mn, max(a, 3000) - 3000); mx = max(mx, min(b, 3299) - 3000); }
    if (b >= 3300)             { mn = min(mn, max(a, 3300) - 3300); mx = max(mx, b - 3300); }
}

// ---------------- gather: IN[3600][24] + cls rows of x and xb --------------
__global__ __launch_bounds__(256) void gather_kernel(
    const float* __restrict__ pxs, const float* __restrict__ pys, const float* __restrict__ phs,
    const float* __restrict__ bxs, const float* __restrict__ bys, const float* __restrict__ bzs,
    const float* __restrict__ emb_table, const float* __restrict__ ball_emb,
    const float* __restrict__ cls_emb, const int* __restrict__ pidx,
    float* __restrict__ IN, float* __restrict__ x, u16* __restrict__ xb)
{
    int g = blockIdx.x * 256 + threadIdx.x;
    if (g < 3300) {
        float* row = IN + g * 24;
        if (g < 3000) {
            int id = pidx[g];
            #pragma unroll
            for (int e = 0; e < 20; e++) row[e] = emb_table[id * 20 + e];
            row[20] = pxs[g]; row[21] = pys[g]; row[22] = phs[g];
        } else {
            int b = g - 3000;
            #pragma unroll
            for (int e = 0; e < 20; e++) row[e] = ball_emb[e];
            row[20] = bxs[b]; row[21] = bys[b]; row[22] = bzs[b];
        }
        row[23] = 0.f;
    }
    for (int i = g; i < 300 * 512; i += 3840) {
        float v = cls_emb[i & 511];
        x[3300 * 512 + i] = v;
        xb[3300 * 512 + i] = f2bf(v);
    }
}

// ---------------- per-layer weight convert + vt-pad zero -------------------
__global__ __launch_bounds__(256) void w2b4_kernel(
    const float* __restrict__ s0, const float* __restrict__ s1,
    const float* __restrict__ s2, const float* __restrict__ s3,
    u16* __restrict__ dst, u16* __restrict__ vt)
{
    int stride = gridDim.x * 256;
    for (int i = blockIdx.x * 256 + threadIdx.x; i < 786432; i += stride) {
        const float4* src;
        int j = i;
        if (j < 196608)      { src = (const float4*)s0; }
        else if (j < 262144) { src = (const float4*)s1; j -= 196608; }
        else if (j < 524288) { src = (const float4*)s2; j -= 262144; }
        else                 { src = (const float4*)s3; j -= 524288; }
        float4 v = src[j];
        ushort4 o;
        o.x = f2bf(v.x); o.y = f2bf(v.y); o.z = f2bf(v.z); o.w = f2bf(v.w);
        reinterpret_cast<ushort4*>(dst)[i] = o;
    }
    // zero vt's pad tokens [3600,3648) on all 512 rows
    for (int i = blockIdx.x * 256 + threadIdx.x; i < 512 * 64; i += stride) {
        int row = i >> 6, c = i & 63;
        if (c < 48) vt[(size_t)row * VT_S + 3600 + c] = 0;
    }
}

// ---------------- head-weight + bias pack ----------------------------------
__global__ __launch_bounds__(256) void w2bh_kernel(
    const float* __restrict__ cp, const float* __restrict__ cb,
    const float* __restrict__ cs, const float* __restrict__ bp,
    const float* __restrict__ bb, const float* __restrict__ bs,
    u16* __restrict__ dst, float* __restrict__ bias)
{
    int stride = gridDim.x * 256;
    for (int i = blockIdx.x * 256 + threadIdx.x; i < 187136; i += stride) {
        const float4* src;
        int j = i;
        if (j < 15488)       { src = (const float4*)cp; }
        else if (j < 185856) { src = (const float4*)cb; j -= 15488; }
        else                 { src = (const float4*)cs; j -= 185856; }
        float4 v = src[j];
        ushort4 o;
        o.x = f2bf(v.x); o.y = f2bf(v.y); o.z = f2bf(v.z); o.w = f2bf(v.w);
        reinterpret_cast<ushort4*>(dst)[i] = o;
    }
    int g = blockIdx.x * 256 + threadIdx.x;
    if (g < 1462)
        bias[g] = (g < 121) ? bp[g] : (g < 1452) ? bb[g - 121] : bs[g - 1452];
}

// ---------------- fp32-input token GEMM: player(z=0) / ball(z=1) ----------
__device__ __forceinline__ void stage_f32(
    const float* __restrict__ src, int nrows, int K, int lda,
    int r0, int kk, int srow, int scg, u16* dst)
{
    u16 tmp[16];
    int rr = r0 + srow;
    if (rr < nrows) {
        if (((lda & 3) == 0) && (kk + scg + 16 <= K)) {
            const float4* p = reinterpret_cast<const float4*>(src + (size_t)rr * lda + kk + scg);
            #pragma unroll
            for (int q = 0; q < 4; q++) {
                float4 v = p[q];
                tmp[q*4+0] = f2bf(v.x); tmp[q*4+1] = f2bf(v.y);
                tmp[q*4+2] = f2bf(v.z); tmp[q*4+3] = f2bf(v.w);
            }
        } else {
            #pragma unroll
            for (int e = 0; e < 16; e++) {
                int kc = kk + scg + e;
                tmp[e] = (kc < K) ? f2bf(src[(size_t)rr * lda + kc]) : (u16)0;
            }
        }
    } else {
        #pragma unroll
        for (int e = 0; e < 16; e++) tmp[e] = 0;
    }
    *reinterpret_cast<bf16x8*>(dst)     = *reinterpret_cast<const bf16x8*>(&tmp[0]);
    *reinterpret_cast<bf16x8*>(dst + 8) = *reinterpret_cast<const bf16x8*>(&tmp[8]);
}

template<int RELU, int DUAL>
__global__ __launch_bounds__(256) void gemm_tok(
    const float* __restrict__ A0, const float* __restrict__ W0p,
    const float* __restrict__ b0p, float* __restrict__ C0,
    const float* __restrict__ A1, const float* __restrict__ W1p,
    const float* __restrict__ b1p, float* __restrict__ C1,
    u16* __restrict__ Cb,
    int M0, int M1, int N, int K, int lda, float scale)
{
    int zz = blockIdx.z;
    int M = zz ? M1 : M0;
    int m0 = blockIdx.x * 128;
    if (m0 >= M) return;
    const float* A = zz ? A1 : A0;
    const float* W = zz ? W1p : W0p;
    const float* bias = zz ? b1p : b0p;
    float* C = zz ? C1 : C0;
    u16* CbL = DUAL ? (zz ? Cb + (size_t)M0 * N : Cb) : nullptr;

    __shared__ u16 As[128][40];
    __shared__ u16 Bs[128][40];
    int t = threadIdx.x;
    int w = t >> 6, l = t & 63;
    int ll = l & 15, lg = l >> 4;
    int wr = w >> 1, wc = w & 1;
    int n0 = blockIdx.y * 128;
    int srow = t >> 1;
    int scg  = (t & 1) * 16;

    f32x4 acc[4][4];
    #pragma unroll
    for (int i = 0; i < 4; i++)
        #pragma unroll
        for (int j = 0; j < 4; j++) acc[i][j] = (f32x4){0.f, 0.f, 0.f, 0.f};

    for (int kk = 0; kk < K; kk += 32) {
        stage_f32(A, M, K, lda, m0, kk, srow, scg, &As[srow][scg]);
        stage_f32(W, N, K, K, n0, kk, srow, scg, &Bs[srow][scg]);
        __syncthreads();
        bf16x8 af[4], bf[4];
        #pragma unroll
        for (int i = 0; i < 4; i++)
            af[i] = *reinterpret_cast<const bf16x8*>(&As[wr*64 + i*16 + ll][lg*8]);
        #pragma unroll
        for (int j = 0; j < 4; j++)
            bf[j] = *reinterpret_cast<const bf16x8*>(&Bs[wc*64 + j*16 + ll][lg*8]);
        #pragma unroll
        for (int i = 0; i < 4; i++)
            #pragma unroll
            for (int j = 0; j < 4; j++)
                acc[i][j] = __builtin_amdgcn_mfma_f32_16x16x32_bf16(af[i], bf[j], acc[i][j], 0, 0, 0);
        __syncthreads();
    }

    float bv[4];
    #pragma unroll
    for (int j = 0; j < 4; j++) {
        int n = n0 + wc*64 + j*16 + ll;
        bv[j] = (n < N) ? bias[n] : 0.f;
    }
    #pragma unroll
    for (int i = 0; i < 4; i++) {
        #pragma unroll
        for (int r = 0; r < 4; r++) {
            int m = m0 + wr*64 + i*16 + lg*4 + r;
            if (m >= M) continue;
            #pragma unroll
            for (int j = 0; j < 4; j++) {
                int n = n0 + wc*64 + j*16 + ll;
                if (n >= N) continue;
                float v = acc[i][j][r] + bv[j];
                if (RELU) v = fmaxf(v, 0.f);
                v *= scale;
                C[(size_t)m * N + n] = v;
                if (DUAL) CbL[(size_t)m * N + n] = f2bf(v);
            }
        }
    }
}

// ---------------- bf16 MFMA GEMM, depth-2 pipelined (counted vmcnt) --------
// 3 LDS buffers; tile t+2 staged before computing tile t; raw s_barrier with
// s_waitcnt vmcnt(4) -> prefetch loads stay in flight ACROSS the barrier (T4).
template<int RELU, int BF16OUT, int QSCALE, int SPLITK, int HEADS, int VTOUT>
__global__ __launch_bounds__(256) void gemm_async(
    const u16* __restrict__ A, const u16* __restrict__ W,
    const float* __restrict__ bias, void* __restrict__ Cv, float* __restrict__ C1,
    u16* __restrict__ vtp, int M, int N, int K, int lda, float scale)
{
    __shared__ u16 As[3][4096];   // [buf][128][32]
    __shared__ u16 Bs[3][4096];
    int t = threadIdx.x;
    int w = t >> 6, l = t & 63;
    int ll = l & 15, lg = l >> 4;
    int wr = w >> 1, wc = w & 1;
    int m0 = blockIdx.x * 128, n0 = blockIdx.y * 128;
    int srow = l >> 2;
    int skg  = (l & 3) * 8;
    int kz = SPLITK ? blockIdx.z : 0;
    int khalf = SPLITK ? (K >> 1) : K;
    int kbeg = kz * khalf;
    int nt = khalf >> 5;   // K-steps of 32 (>= 8 for all call sites)

    const u16* pa0 = A + (size_t)min(m0 + w * 16 + srow, M - 1) * lda + skg;
    const u16* pa1 = A + (size_t)min(m0 + 64 + w * 16 + srow, M - 1) * lda + skg;
    const u16* pb0 = W + (size_t)min(n0 + w * 16 + srow, N - 1) * K + skg;
    const u16* pb1 = W + (size_t)min(n0 + 64 + w * 16 + srow, N - 1) * K + skg;
    int la0 = (w * 16) * 32;
    int la1 = (64 + w * 16) * 32;

    f32x4 acc[4][4];
    #pragma unroll
    for (int i = 0; i < 4; i++)
        #pragma unroll
        for (int j = 0; j < 4; j++) acc[i][j] = (f32x4){0.f, 0.f, 0.f, 0.f};

    // prologue: stage tiles 0 and 1 (nt >= 2 always)
    async_ld16(pa0 + kbeg, &As[0][la0]);
    async_ld16(pa1 + kbeg, &As[0][la1]);
    async_ld16(pb0 + kbeg, &Bs[0][la0]);
    async_ld16(pb1 + kbeg, &Bs[0][la1]);
    {
        int k1 = kbeg + 32;
        async_ld16(pa0 + k1, &As[1][la0]);
        async_ld16(pa1 + k1, &As[1][la1]);
        async_ld16(pb0 + k1, &Bs[1][la0]);
        async_ld16(pb1 + k1, &Bs[1][la1]);
    }
    asm volatile("s_waitcnt vmcnt(4)" ::: "memory");   // tile 0 landed
    __builtin_amdgcn_s_barrier();

    int cur = 0, nb = 2;
    for (int it = 0; it < nt; ++it) {
        if (it + 2 < nt) {
            int kn = kbeg + ((it + 2) << 5);
            async_ld16(pa0 + kn, &As[nb][la0]);
            async_ld16(pa1 + kn, &As[nb][la1]);
            async_ld16(pb0 + kn, &Bs[nb][la0]);
            async_ld16(pb1 + kn, &Bs[nb][la1]);
            asm volatile("s_waitcnt vmcnt(4)" ::: "memory");  // tile it+1 landed
        } else {
            asm volatile("s_waitcnt vmcnt(0)" ::: "memory");  // tail: drain all
        }
        bf16x8 af[4], bf[4];
        #pragma unroll
        for (int i = 0; i < 4; i++)
            af[i] = *reinterpret_cast<const bf16x8*>(&As[cur][(wr*64 + i*16 + ll) * 32 + lg*8]);
        #pragma unroll
        for (int j = 0; j < 4; j++)
            bf[j] = *reinterpret_cast<const bf16x8*>(&Bs[cur][(wc*64 + j*16 + ll) * 32 + lg*8]);
        #pragma unroll
        for (int i = 0; i < 4; i++)
            #pragma unroll
            for (int j = 0; j < 4; j++)
                acc[i][j] = __builtin_amdgcn_mfma_f32_16x16x32_bf16(af[i], bf[j], acc[i][j], 0, 0, 0);
        __builtin_amdgcn_s_barrier();  // raw: prefetch stays in flight
        cur = (cur == 2) ? 0 : cur + 1;
        nb  = (nb == 2) ? 0 : nb + 1;
    }

    float bv[4];
    #pragma unroll
    for (int j = 0; j < 4; j++) {
        int n = n0 + wc*64 + j*16 + ll;
        bv[j] = (n < N && (!SPLITK || kz == 0)) ? bias[n] : 0.f;
    }
    #pragma unroll
    for (int i = 0; i < 4; i++) {
        if (VTOUT) {
            #pragma unroll
            for (int j = 0; j < 4; j++) {
                int n = n0 + wc*64 + j*16 + ll;
                int mb = m0 + wr*64 + i*16 + lg*4;
                if (n >= 1024) {
                    if (mb < T_TOK) {
                        ushort4 o;
                        o.x = f2bf(acc[i][j][0] + bv[j]);
                        o.y = f2bf(acc[i][j][1] + bv[j]);
                        o.z = f2bf(acc[i][j][2] + bv[j]);
                        o.w = f2bf(acc[i][j][3] + bv[j]);
                        *reinterpret_cast<ushort4*>(vtp + (size_t)(n - 1024) * VT_S + mb) = o;
                    }
                } else {
                    #pragma unroll
                    for (int r = 0; r < 4; r++) {
                        int mm = mb + r;
                        if (mm >= M) continue;
                        float v = acc[i][j][r] + bv[j];
                        if (n < 512) v *= QK_SCALE;
                        ((u16*)Cv)[(size_t)mm * QKS + n] = f2bf(v);
                    }
                }
            }
        } else {
            #pragma unroll
            for (int r = 0; r < 4; r++) {
                int m = m0 + wr*64 + i*16 + lg*4 + r;
                if (m >= M) continue;
                #pragma unroll
                for (int j = 0; j < 4; j++) {
                    int n = n0 + wc*64 + j*16 + ll;
                    if (n >= N) continue;
                    float v = acc[i][j][r] + bv[j];
                    if (RELU) v = fmaxf(v, 0.f);
                    v *= scale;
                    if (QSCALE && n < 512) v *= QK_SCALE;
                    if (HEADS) {
                        float* o = (float*)Cv;
                        if (n < 121)       o[(size_t)m * 121 + n] = v;
                        else if (n < 1452) (o + 435600)[(size_t)m * 1331 + (n - 121)] = v;
                        else               (o + 5227200)[(size_t)m * 10 + (n - 1452)] = v;
                    } else if (SPLITK && kz == 1) {
                        C1[(size_t)m * N + n] = v;
                    } else if (BF16OUT) {
                        ((u16*)Cv)[(size_t)m * N + n] = f2bf(v);
                    } else {
                        ((float*)Cv)[(size_t)m * N + n] = v;
                    }
                }
            }
        }
    }
}

// ---------------- MFMA flash attention: 32 q/wave, swapped QK^T ------------
// grid 7232 = 113 ranks x 8 z x 8 heads (1 q-tile per wave; rank-major LPT).
__global__ __launch_bounds__(64) void attn_mfma_kernel(
    const u16* __restrict__ qkvb, const u16* __restrict__ vt,
    u16* __restrict__ Op0, u16* __restrict__ Op1, float* __restrict__ mlpart)
{
    __shared__ u16 plds[2][16][66];
    int l = threadIdx.x;
    int lg = l >> 4, ll = l & 15;
    int bid = blockIdx.x;
    int h = bid & 7;
    int rest = bid >> 3;      // 0..903
    int z = rest & 7;         // 0..7
    int rank = rest >> 3;     // 0..112
    int q0 = (112 - rank) * 32;

    bf16x8 qf0[2], qf1[2];
    int sql[2];
    bool qok[2];
    #pragma unroll
    for (int b = 0; b < 2; b++) {
        int qa = q0 + b * 16 + ll;
        qok[b] = qa < T_TOK;
        int qac = min(qa, T_TOK - 1);
        const u16* qrow = qkvb + (size_t)qac * QKS + h * HD + lg * 8;
        qf0[b] = *reinterpret_cast<const bf16x8*>(qrow);
        qf1[b] = *reinterpret_cast<const bf16x8*>(qrow + 32);
        sql[b] = step_of(qac);
    }
    int sl = max(sql[0], sql[1]), s2 = min(sql[0], sql[1]);
    #pragma unroll
    for (int off = 1; off < 16; off <<= 1) {
        sl = max(sl, __shfl_xor(sl, off));
        s2 = min(s2, __shfl_xor(s2, off));
    }
    int smax = sl, smin = s2;
    int limp[2], limb[2], limc[2];
    #pragma unroll
    for (int b = 0; b < 2; b++) {
        limp[b] = sql[b] * 10 + 9;
        limb[b] = 3000 + sql[b];
        limc[b] = 3300 + sql[b];
    }

    f32x4 oacc[2][4];
    #pragma unroll
    for (int b = 0; b < 2; b++)
        #pragma unroll
        for (int i = 0; i < 4; i++) oacc[b][i] = (f32x4){0.f, 0.f, 0.f, 0.f};
    float m[2] = {-INFINITY, -INFINITY};
    float ls[2] = {0.f, 0.f};

    #pragma unroll 1
    for (int kt = z; kt < NKT; kt += KSPLIT) {
        int kbase = kt * 64;
        int mn, mx;
        tile_minmax(kbase, mn, mx);
        if (mn > smax) continue;
        bool needmask = (mx > smin) || (kbase + 64 > T_TOK);

        bf16x8 kf0[4], kf1[4];
        #pragma unroll
        for (int f = 0; f < 4; f++) {
            int keyc = min(kbase + f * 16 + ll, T_TOK - 1);
            const u16* kr = qkvb + (size_t)keyc * QKS + 512 + h * HD + lg * 8;
            kf0[f] = *reinterpret_cast<const bf16x8*>(kr);
            kf1[f] = *reinterpret_cast<const bf16x8*>(kr + 32);
        }
        bf16x8 vf0[4], vf1[4];
        #pragma unroll
        for (int i = 0; i < 4; i++) {
            const u16* vr = vt + (size_t)(h * HD + i * 16 + ll) * VT_S + kbase + lg * 8;
            vf0[i] = *reinterpret_cast<const bf16x8*>(vr);
            vf1[i] = *reinterpret_cast<const bf16x8*>(vr + 32);
        }

        f32x4 sfr[2][4];
        __builtin_amdgcn_s_setprio(1);
        #pragma unroll
        for (int f = 0; f < 4; f++) {
            #pragma unroll
            for (int b = 0; b < 2; b++) {
                f32x4 acc = (f32x4){0.f, 0.f, 0.f, 0.f};
                acc = __builtin_amdgcn_mfma_f32_16x16x32_bf16(kf0[f], qf0[b], acc, 0, 0, 0);
                acc = __builtin_amdgcn_mfma_f32_16x16x32_bf16(kf1[f], qf1[b], acc, 0, 0, 0);
                sfr[b][f] = acc;
            }
        }
        __builtin_amdgcn_s_setprio(0);

        float rmax[2] = {-INFINITY, -INFINITY};
        if (!needmask) {
            #pragma unroll
            for (int f = 0; f < 4; f++)
                #pragma unroll
                for (int b = 0; b < 2; b++)
                    #pragma unroll
                    for (int r = 0; r < 4; r++) rmax[b] = fmaxf(rmax[b], sfr[b][f][r]);
        } else {
            #pragma unroll
            for (int f = 0; f < 4; f++)
                #pragma unroll
                for (int r = 0; r < 4; r++) {
                    int key = kbase + f * 16 + lg * 4 + r;
                    #pragma unroll
                    for (int b = 0; b < 2; b++) {
                        int lim = (key < 3000) ? limp[b] : ((key < 3300) ? limb[b] : limc[b]);
                        float v = sfr[b][f][r];
                        v = (key <= lim) ? v : -INFINITY;
                        sfr[b][f][r] = v;
                        rmax[b] = fmaxf(rmax[b], v);
                    }
                }
        }
        if (!qok[0]) rmax[0] = -INFINITY;
        if (!qok[1]) rmax[1] = -INFINITY;
        #pragma unroll
        for (int b = 0; b < 2; b++) {
            rmax[b] = fmaxf(rmax[b], __shfl_xor(rmax[b], 16));
            rmax[b] = fmaxf(rmax[b], __shfl_xor(rmax[b], 32));
        }
        bool upd = (rmax[0] > m[0] + 8.f) || (rmax[1] > m[1] + 8.f);
        if (__any(upd)) {
            #pragma unroll
            for (int b = 0; b < 2; b++) {
                float mn2 = fmaxf(m[b], rmax[b]);
                float c = (m[b] == -INFINITY) ? 0.f : exp2f(m[b] - mn2);
                m[b] = mn2;
                ls[b] *= c;
                f32x4 cv;
                cv[0] = __shfl(c, lg * 4 + 0);
                cv[1] = __shfl(c, lg * 4 + 1);
                cv[2] = __shfl(c, lg * 4 + 2);
                cv[3] = __shfl(c, lg * 4 + 3);
                #pragma unroll
                for (int i = 0; i < 4; i++) {
                    oacc[b][i][0] *= cv[0]; oacc[b][i][1] *= cv[1];
                    oacc[b][i][2] *= cv[2]; oacc[b][i][3] *= cv[3];
                }
            }
        }
        if (!needmask) {
            #pragma unroll
            for (int b = 0; b < 2; b++)
                #pragma unroll
                for (int f = 0; f < 4; f++) {
                    float p0 = exp2f(sfr[b][f][0] - m[b]);
                    float p1 = exp2f(sfr[b][f][1] - m[b]);
                    float p2 = exp2f(sfr[b][f][2] - m[b]);
                    float p3 = exp2f(sfr[b][f][3] - m[b]);
                    ls[b] += (p0 + p1) + (p2 + p3);
                    *reinterpret_cast<u32*>(&plds[b][ll][f * 16 + lg * 4])     = cvt_pk_bf16(p0, p1);
                    *reinterpret_cast<u32*>(&plds[b][ll][f * 16 + lg * 4 + 2]) = cvt_pk_bf16(p2, p3);
                }
        } else {
            #pragma unroll
            for (int b = 0; b < 2; b++)
                #pragma unroll
                for (int f = 0; f < 4; f++) {
                    float sv0 = sfr[b][f][0], sv1 = sfr[b][f][1];
                    float sv2 = sfr[b][f][2], sv3 = sfr[b][f][3];
                    float p0 = (sv0 == -INFINITY) ? 0.f : exp2f(sv0 - m[b]);
                    float p1 = (sv1 == -INFINITY) ? 0.f : exp2f(sv1 - m[b]);
                    float p2 = (sv2 == -INFINITY) ? 0.f : exp2f(sv2 - m[b]);
                    float p3 = (sv3 == -INFINITY) ? 0.f : exp2f(sv3 - m[b]);
                    ls[b] += (p0 + p1) + (p2 + p3);
                    *reinterpret_cast<u32*>(&plds[b][ll][f * 16 + lg * 4])     = cvt_pk_bf16(p0, p1);
                    *reinterpret_cast<u32*>(&plds[b][ll][f * 16 + lg * 4 + 2]) = cvt_pk_bf16(p2, p3);
                }
        }
        __builtin_amdgcn_s_setprio(1);
        #pragma unroll
        for (int b = 0; b < 2; b++) {
            bf16x8 pf0 = *reinterpret_cast<const bf16x8*>(&plds[b][ll][lg * 8]);
            #pragma unroll
            for (int i = 0; i < 4; i++)
                oacc[b][i] = __builtin_amdgcn_mfma_f32_16x16x32_bf16(pf0, vf0[i], oacc[b][i], 0, 0, 0);
            bf16x8 pf1 = *reinterpret_cast<const bf16x8*>(&plds[b][ll][32 + lg * 8]);
            #pragma unroll
            for (int i = 0; i < 4; i++)
                oacc[b][i] = __builtin_amdgcn_mfma_f32_16x16x32_bf16(pf1, vf1[i], oacc[b][i], 0, 0, 0);
        }
        __builtin_amdgcn_s_setprio(0);
    }

    #pragma unroll
    for (int b = 0; b < 2; b++) {
        ls[b] += __shfl_xor(ls[b], 16);
        ls[b] += __shfl_xor(ls[b], 32);
    }
    u16* Ob = (z < 5) ? (Op0 + (size_t)z * ZSLICE) : (Op1 + (size_t)(z - 5) * ZSLICE);
    #pragma unroll
    for (int b = 0; b < 2; b++)
        #pragma unroll
        for (int r = 0; r < 4; r++) {
            int q = q0 + b * 16 + lg * 4 + r;
            if (q >= T_TOK) continue;
            size_t ob = ((size_t)h * 3600 + q) * 64;
            #pragma unroll
            for (int i = 0; i < 4; i++)
                Ob[ob + i * 16 + ll] = f2bf(oacc[b][i][r]);
        }
    if (lg == 0) {
        #pragma unroll
        for (int b = 0; b < 2; b++) {
            int qa = q0 + b * 16 + ll;
            if (qa < T_TOK) {
                size_t mi = ((size_t)(z * 8 + h) * 3600 + qa) * 2;
                mlpart[mi]     = m[b];
                mlpart[mi + 1] = ls[b];
            }
        }
    }
}

// ---------------- merge KSPLIT partials -> obb (vectorized) ----------------
__global__ __launch_bounds__(256) void attn_merge_kernel(
    const u16* __restrict__ Op0, const u16* __restrict__ Op1,
    const float* __restrict__ mlpart, u16* __restrict__ obb)
{
    int t = threadIdx.x;
    int h = blockIdx.y;
    int q = blockIdx.x * 64 + (t >> 2);
    if (q >= T_TOK) return;
    int dg = (t & 3) * 16;
    float mz[KSPLIT], lz[KSPLIT];
    #pragma unroll
    for (int zz = 0; zz < KSPLIT; zz++) {
        size_t mi = ((size_t)(zz * 8 + h) * 3600 + q) * 2;
        mz[zz] = mlpart[mi];
        lz[zz] = mlpart[mi + 1];
    }
    float M = -INFINITY;
    #pragma unroll
    for (int zz = 0; zz < KSPLIT; zz++) if (lz[zz] > 0.f) M = fmaxf(M, mz[zz]);
    float wz[KSPLIT], den = 0.f;
    #pragma unroll
    for (int zz = 0; zz < KSPLIT; zz++) {
        wz[zz] = (lz[zz] > 0.f) ? exp2f(mz[zz] - M) : 0.f;
        den += wz[zz] * lz[zz];
    }
    float inv = (den > 0.f) ? 1.f / den : 0.f;
    size_t qoff = ((size_t)h * 3600 + q) * 64 + dg;
    float acc[16];
    #pragma unroll
    for (int e = 0; e < 16; e++) acc[e] = 0.f;
    #pragma unroll
    for (int zz = 0; zz < KSPLIT; zz++) {
        const u16* Ob = (zz < 5) ? (Op0 + (size_t)zz * ZSLICE) : (Op1 + (size_t)(zz - 5) * ZSLICE);
        bf16x8 v0 = *reinterpret_cast<const bf16x8*>(Ob + qoff);
        bf16x8 v1 = *reinterpret_cast<const bf16x8*>(Ob + qoff + 8);
        float w = wz[zz];
        #pragma unroll
        for (int e = 0; e < 8; e++) {
            acc[e]     += bf2f((u16)v0[e]) * w;
            acc[8 + e] += bf2f((u16)v1[e]) * w;
        }
    }
    u16 o16[16];
    #pragma unroll
    for (int e = 0; e < 16; e++) o16[e] = f2bf(acc[e] * inv);
    u16* op = obb + (size_t)q * D_ + h * HD + dg;
    *reinterpret_cast<bf16x8*>(op)     = *reinterpret_cast<const bf16x8*>(&o16[0]);
    *reinterpret_cast<bf16x8*>(op + 8) = *reinterpret_cast<const bf16x8*>(&o16[8]);
}

// ---------------- residual add (two partials) + LayerNorm (float4) --------
__global__ __launch_bounds__(128) void add_ln3_kernel(
    float* __restrict__ x, const float* __restrict__ r1, const float* __restrict__ r2,
    const float* __restrict__ g, const float* __restrict__ b,
    u16* __restrict__ xb)
{
    int row = blockIdx.x, t = threadIdx.x;   // 128 threads, 4 elems each
    size_t base = (size_t)row * D_ + t * 4;
    float4 xv = *reinterpret_cast<const float4*>(&x[base]);
    float4 a1 = *reinterpret_cast<const float4*>(&r1[base]);
    float4 a2 = *reinterpret_cast<const float4*>(&r2[base]);
    float v0 = xv.x + a1.x + a2.x;
    float v1 = xv.y + a1.y + a2.y;
    float v2 = xv.z + a1.z + a2.z;
    float v3 = xv.w + a1.w + a2.w;
    float s = (v0 + v1) + (v2 + v3);
    float ss = (v0 * v0 + v1 * v1) + (v2 * v2 + v3 * v3);
    #pragma unroll
    for (int off = 32; off > 0; off >>= 1) {
        s  += __shfl_xor(s, off);
        ss += __shfl_xor(ss, off);
    }
    __shared__ float rs[2], rss[2];
    int w = t >> 6;
    if ((t & 63) == 0) { rs[w] = s; rss[w] = ss; }
    __syncthreads();
    s  = rs[0] + rs[1];
    ss = rss[0] + rss[1];
    float mean = s * (1.f / 512.f);
    float var = ss * (1.f / 512.f) - mean * mean;
    float rstd = rsqrtf(var + 1e-5f);
    float4 gv = *reinterpret_cast<const float4*>(&g[t * 4]);
    float4 bv = *reinterpret_cast<const float4*>(&b[t * 4]);
    float o0 = (v0 - mean) * rstd * gv.x + bv.x;
    float o1 = (v1 - mean) * rstd * gv.y + bv.y;
    float o2 = (v2 - mean) * rstd * gv.z + bv.z;
    float o3 = (v3 - mean) * rstd * gv.w + bv.w;
    *reinterpret_cast<float4*>(&x[base]) = make_float4(o0, o1, o2, o3);
    ushort4 ob;
    ob.x = f2bf(o0); ob.y = f2bf(o1); ob.z = f2bf(o2); ob.w = f2bf(o3);
    *reinterpret_cast<ushort4*>(&xb[base]) = ob;
}

// ---------------------------------------------------------------------------
extern "C" void kernel_launch(void* const* d_in, const int* in_sizes, int n_in,
                              void* d_out, int out_size, void* d_ws, size_t ws_size,
                              hipStream_t stream)
{
    const float* player_xs = (const float*)d_in[0];
    const float* player_ys = (const float*)d_in[1];
    const float* player_hs = (const float*)d_in[2];
    const float* ball_xs   = (const float*)d_in[3];
    const float* ball_ys   = (const float*)d_in[4];
    const float* ball_zs   = (const float*)d_in[5];
    const float* emb_table = (const float*)d_in[6];
    const float* ball_emb  = (const float*)d_in[7];
    const float* cls_emb   = (const float*)d_in[8];
    const float* pW0 = (const float*)d_in[9];   const float* pb0 = (const float*)d_in[10];
    const float* pW1 = (const float*)d_in[11];  const float* pb1 = (const float*)d_in[12];
    const float* pW2 = (const float*)d_in[13];  const float* pb2 = (const float*)d_in[14];
    const float* bW0 = (const float*)d_in[15];  const float* bb0 = (const float*)d_in[16];
    const float* bW1 = (const float*)d_in[17];  const float* bb1 = (const float*)d_in[18];
    const float* bW2 = (const float*)d_in[19];  const float* bb2 = (const float*)d_in[20];
    const float* Wqkv = (const float*)d_in[21]; const float* bqkv = (const float*)d_in[22];
    const float* Wo  = (const float*)d_in[23];  const float* bo  = (const float*)d_in[24];
    const float* W1f = (const float*)d_in[25];  const float* b1f = (const float*)d_in[26];
    const float* W2f = (const float*)d_in[27];  const float* b2f = (const float*)d_in[28];
    const float* g1  = (const float*)d_in[29];  const float* be1 = (const float*)d_in[30];
    const float* g2  = (const float*)d_in[31];  const float* be2 = (const float*)d_in[32];
    const float* cpW = (const float*)d_in[33];  const float* cpb = (const float*)d_in[34];
    const float* cbW = (const float*)d_in[35];  const float* cbb = (const float*)d_in[36];
    const float* csW = (const float*)d_in[37];  const float* csb = (const float*)d_in[38];
    const int* pidx = (const int*)d_in[39];

    // workspace (51.6 MB): x | big | obr | tmp2
    float* x    = (float*)d_ws;            // 1,843,200 f32
    float* big  = x + 1843200;             // 7,372,800 f32
    float* obr  = big + 7372800;           // 1,843,200 f32
    float* tmp2 = obr + 1843200;           // 1,843,200 f32
    u16*   qkvb   = (u16*)big;             // [3600][1024] bf16 (Q|K, compact)
    u16*   Op0    = (u16*)(big + 2764800); // z-slices 0-4
    u16*   wbh    = (u16*)(big + 6681600); // head weights bf16
    float* bhead  = big + 7100000;         // packed head bias
    u16*   ff1b   = (u16*)big;             // [3600][2048] bf16 (FF phase)
    float* r2buf  = big + 4000000;         // split-K second partial
    u16*   obb    = (u16*)obr;             // [3600][512] bf16
    u16*   xb     = (u16*)(obr + 921600);  // [3600][512] bf16
    u16*   vt     = (u16*)tmp2;            // [512][3648] bf16
    float* mlpart = tmp2 + 1000000;        // [8][8][3600][2] f32
    float* out = (float*)d_out;
    u16* wpack  = (u16*)d_out;
    u16* wqkv_b = wpack;                   // 1536*512
    u16* wo_b   = wpack + 786432;          // 512*512
    u16* w1f_b  = wpack + 1048576;         // 2048*512
    u16* w2f_b  = wpack + 2097152;         // 512*2048
    u16* Op1    = wpack + 3145728;         // z-slices 5-7
    float* IN = big;                       // 3600*24
    float* h0 = big + 131072;              // 3600*128
    float* h1 = big + 131072 + 460800;     // 3600*256

    gather_kernel<<<15, 256, 0, stream>>>(
        player_xs, player_ys, player_hs, ball_xs, ball_ys, ball_zs,
        emb_table, ball_emb, cls_emb, pidx, IN, x, xb);

    gemm_tok<1,0><<<dim3(24, 1, 2), 256, 0, stream>>>(
        IN, pW0, pb0, h0, IN + 3000*24, bW0, bb0, h0 + 3000*128, nullptr,
        3000, 300, 128, 23, 24, 1.f);
    gemm_tok<1,0><<<dim3(24, 2, 2), 256, 0, stream>>>(
        h0, pW1, pb1, h1, h0 + 3000*128, bW1, bb1, h1 + 3000*256, nullptr,
        3000, 300, 256, 128, 128, 1.f);
    gemm_tok<0,1><<<dim3(24, 4, 2), 256, 0, stream>>>(
        h1, pW2, pb2, x, h1 + 3000*256, bW2, bb2, x + 3000*512, xb,
        3000, 300, 512, 256, 256, SQRT512);

    for (int l = 0; l < 4; l++) {
        const float* Wqkv_l = Wqkv + (size_t)l * 1536 * 512;
        const float* bqkv_l = bqkv + (size_t)l * 1536;
        const float* bo_l   = bo   + (size_t)l * 512;
        const float* Wo_l   = Wo   + (size_t)l * 512 * 512;
        const float* W1f_l  = W1f  + (size_t)l * 2048 * 512;
        const float* b1f_l  = b1f  + (size_t)l * 2048;
        const float* W2f_l  = W2f  + (size_t)l * 512 * 2048;
        const float* b2f_l  = b2f  + (size_t)l * 512;

        w2b4_kernel<<<1024, 256, 0, stream>>>(Wqkv_l, Wo_l, W1f_l, W2f_l, wpack, vt);
        gemm_async<0,1,1,0,0,1><<<dim3(29, 12), 256, 0, stream>>>(xb, wqkv_b, bqkv_l, qkvb, nullptr, vt, 3600, 1536, 512, 512, 1.f);
        attn_mfma_kernel<<<113 * 8 * 8, 64, 0, stream>>>(qkvb, vt, Op0, Op1, mlpart);
        attn_merge_kernel<<<dim3(57, 8), 256, 0, stream>>>(Op0, Op1, mlpart, obb);
        gemm_async<0,0,0,1,0,0><<<dim3(29, 4, 2), 256, 0, stream>>>(obb, wo_b, bo_l, tmp2, r2buf, nullptr, 3600, 512, 512, 512, 1.f);
        add_ln3_kernel<<<3600, 128, 0, stream>>>(x, tmp2, r2buf, g1 + (size_t)l * 512, be1 + (size_t)l * 512, xb);
        gemm_async<1,1,0,0,0,0><<<dim3(29, 16), 256, 0, stream>>>(xb, w1f_b, b1f_l, ff1b, nullptr, nullptr, 3600, 2048, 512, 512, 1.f);
        gemm_async<0,0,0,1,0,0><<<dim3(29, 4, 2), 256, 0, stream>>>(ff1b, w2f_b, b2f_l, tmp2, r2buf, nullptr, 3600, 512, 2048, 2048, 1.f);
        add_ln3_kernel<<<3600, 128, 0, stream>>>(x, tmp2, r2buf, g2 + (size_t)l * 512, be2 + (size_t)l * 512, xb);
    }

    w2bh_kernel<<<732, 256, 0, stream>>>(cpW, cbW, csW, cpb, cbb, csb, wbh, bhead);
    gemm_async<0,0,0,0,1,0><<<dim3(29, 12), 256, 0, stream>>>(xb, wbh, bhead, out, nullptr, nullptr, 3600, 1462, 512, 512, 1.f);
}